// Round 8
// baseline (4551.564 us; speedup 1.0000x reference)
//
#include <hip/hip_runtime.h>
#include <math.h>

// Problem constants (fixed by the reference module)
#define HSZ   512
#define H4    2048
#define SEQ   64
#define VOC   32000
#define BEAM  3
#define TMAX  50
#define NBLK  256
#define NTHR  512
#define FLS   16        // flag line stride in ints (64 B)

#define LOFF  ((size_t)H4 * HSZ)   // per-layer weight stride

__device__ __forceinline__ float wsum(float v) {
#pragma unroll
  for (int off = 32; off; off >>= 1) v += __shfl_xor(v, off, 64);
  return v;
}
__device__ __forceinline__ float dot4(float4 a, float4 b) {
  return a.x * b.x + a.y * b.y + a.z * b.z + a.w * b.w;
}
__device__ __forceinline__ float sigf(float x) { return 1.f / (1.f + expf(-x)); }

__device__ __forceinline__ bool better(float v1, int i1, float v2, int i2) {
  return (v1 > v2) || (v1 == v2 && i1 < i2);  // jax.lax.top_k order: value desc, index asc
}
__device__ __forceinline__ void ins3(float* v, int* idx, float nv, int ni) {
  if (better(nv, ni, v[2], idx[2])) {
    if (better(nv, ni, v[1], idx[1])) {
      v[2] = v[1]; idx[2] = idx[1];
      if (better(nv, ni, v[0], idx[0])) { v[1] = v[0]; idx[1] = idx[0]; v[0] = nv; idx[0] = ni; }
      else { v[1] = nv; idx[1] = ni; }
    } else { v[2] = nv; idx[2] = ni; }
  }
}

// ---- coherent accessors for cross-block state (relaxed, agent scope) ----
__device__ __forceinline__ float agld(const float* p) {
  return __hip_atomic_load(p, __ATOMIC_RELAXED, __HIP_MEMORY_SCOPE_AGENT);
}
__device__ __forceinline__ void agst(float* p, float v) {
  __hip_atomic_store(p, v, __ATOMIC_RELAXED, __HIP_MEMORY_SCOPE_AGENT);
}
__device__ __forceinline__ int agldi(const int* p) {
  return __hip_atomic_load(p, __ATOMIC_RELAXED, __HIP_MEMORY_SCOPE_AGENT);
}
__device__ __forceinline__ void rmw_set(int* p, int ep) {
  __hip_atomic_fetch_max(p, ep, __ATOMIC_RELAXED, __HIP_MEMORY_SCOPE_AGENT);
}

// ---- all-see-all grid barrier: no central collect, no broadcast hop ----
// Each block RMW-bumps its own flag line; thread i of EVERY block spin-loads
// flag line i (read-shared relaxed agent loads; no RMW serialization) until
// it reaches the epoch. Exit latency = last-arrival + one load round.
__device__ __forceinline__ void gbar_all(int* flags, int blk, int tid, int ep) {
  __syncthreads();  // phase writes drained (waitcnt vmcnt(0) precedes s_barrier)
  if (tid == 0) rmw_set(&flags[blk * FLS], ep);
  if (tid < NBLK) {
    long it = 0;
    while (agldi(&flags[tid * FLS]) < ep && it < 200000000L) ++it;  // bailout beats a hang
  }
  asm volatile("" ::: "memory");
  __syncthreads();
}
// second-epoch mini-barrier: block 0 publishes, everyone else polls line 0 only
__device__ __forceinline__ void bar0(int* flags, int blk, int tid, int ep) {
  if (blk == 0) {
    __syncthreads();  // block-0 extra work drained
    if (tid == 0) rmw_set(&flags[0], ep);
  } else {
    if (tid == 0) {
      long it = 0;
      while (agldi(&flags[0]) < ep && it < 200000000L) ++it;
    }
  }
  asm volatile("" ::: "memory");
  __syncthreads();
}

struct Ptrs {
  const int*   seq;
  const float* emb_enc; const float* Wih_enc; const float* Whh_enc; const float* b_enc;
  const float* emb_dec; const float* Wih_dec; const float* Whh_dec; const float* b_dec;
  const float* W_c; const float* W_out; const float* b_out;
  const int*   bosp;
  int* flags;
  float* xp1;
  float* h1a; float* c1a; float* h2a; float* c2a;
  float* hd; float* cd; float* hdn; float* cdn;
  float* x_dec; float* feat;
  float* pm; float* ps; float* pv; int* pi;
  float* scores; int* tokens; int* bt;
  int* outp;
};

// ---------------- encoder phases ----------------

// xp1[t][r] = b_enc[r] + dot(Wih_enc[r], emb_enc[seq[t]]); wave owns row r, lane owns t
__device__ void phase_xw1(const Ptrs& P, int blk, int tid) {
  int t    = tid & 63;
  int wave = tid >> 6;
  int r    = blk * 8 + wave;
  int tok  = P.seq[t];
  const float* xr = P.emb_enc + (size_t)tok * HSZ;
  const float* wr = P.Wih_enc + (size_t)r * HSZ;
  float acc = 0.f;
  for (int e = 0; e < HSZ; e += 4) {
    float4 wv = *(const float4*)(wr + e);
    float4 xv = *(const float4*)(xr + e);
    acc += dot4(wv, xv);
  }
  agst(&P.xp1[t * H4 + r], acc + P.b_enc[r]);
}

// One wavefront slot: layer1 cell t=s (blocks 0..127), layer2 cell t=s-1 (blocks 128..255).
// 4 rows/block, 2 gates/wave; gates recombined in LDS.
__device__ void phase_encslot(const Ptrs& P, float* sm, int blk, int tid, int s) {
  int wave = tid >> 6, lane = tid & 63;
  bool l2  = blk >= 128;
  int t    = l2 ? s - 1 : s;
  if (t < 0 || t >= SEQ) return;
  int bb   = blk & 127;
  int lr   = wave >> 1;            // 0..3 local row
  int j    = bb * 4 + lr;          // 0..511
  int g0   = (wave & 1) * 2;       // gates {g0, g0+1}
  float* rowX = sm;                // 512
  float* rowH = sm + 512;          // 512 (l2 only)
  float* zl   = sm + 1024;         // [4][4]
  if (!l2) {
    rowX[tid] = (t > 0) ? agld(&P.h1a[t * HSZ + tid]) : 0.f;
    __syncthreads();
    float4 h0 = ((const float4*)rowX)[lane], h1v = ((const float4*)rowX)[lane + 64];
#pragma unroll
    for (int gg = 0; gg < 2; ++gg) {
      int g = g0 + gg;
      int row = j + (g << 9);
      const float4* wr = (const float4*)(P.Whh_enc + (size_t)row * HSZ);
      float zs = wsum(dot4(wr[lane], h0) + dot4(wr[lane + 64], h1v));
      if (lane == 0) zl[lr * 4 + g] = zs + agld(&P.xp1[t * H4 + row]);
    }
    __syncthreads();
    if (tid < 4) {
      int j2 = bb * 4 + tid;
      float z0 = zl[tid * 4 + 0], z1 = zl[tid * 4 + 1], z2 = zl[tid * 4 + 2], z3 = zl[tid * 4 + 3];
      float cp = (t > 0) ? agld(&P.c1a[t * HSZ + j2]) : 0.f;
      float c = sigf(z1) * cp + sigf(z0) * tanhf(z2);
      agst(&P.c1a[(t + 1) * HSZ + j2], c);
      agst(&P.h1a[(t + 1) * HSZ + j2], sigf(z3) * tanhf(c));
    }
  } else {
    rowX[tid] = agld(&P.h1a[(t + 1) * HSZ + tid]);
    rowH[tid] = (t > 0) ? agld(&P.h2a[t * HSZ + tid]) : 0.f;
    __syncthreads();
    float4 x0 = ((const float4*)rowX)[lane], x1 = ((const float4*)rowX)[lane + 64];
    float4 h0 = ((const float4*)rowH)[lane], h1v = ((const float4*)rowH)[lane + 64];
#pragma unroll
    for (int gg = 0; gg < 2; ++gg) {
      int g = g0 + gg;
      int row = j + (g << 9);
      const float4* wi = (const float4*)(P.Wih_enc + LOFF + (size_t)row * HSZ);
      const float4* wh = (const float4*)(P.Whh_enc + LOFF + (size_t)row * HSZ);
      float zs = wsum(dot4(wi[lane], x0) + dot4(wi[lane + 64], x1) +
                      dot4(wh[lane], h0) + dot4(wh[lane + 64], h1v));
      if (lane == 0) zl[lr * 4 + g] = zs + P.b_enc[H4 + row];
    }
    __syncthreads();
    if (tid < 4) {
      int j2 = bb * 4 + tid;
      float z0 = zl[tid * 4 + 0], z1 = zl[tid * 4 + 1], z2 = zl[tid * 4 + 2], z3 = zl[tid * 4 + 3];
      float cp = (t > 0) ? agld(&P.c2a[t * HSZ + j2]) : 0.f;
      float c = sigf(z1) * cp + sigf(z0) * tanhf(z2);
      agst(&P.c2a[(t + 1) * HSZ + j2], c);
      agst(&P.h2a[(t + 1) * HSZ + j2], sigf(z3) * tanhf(c));
    }
  }
}

// run by block 0 between the final encoder sync and its bar0 epoch
__device__ void dinit_body(const Ptrs& P, int tid) {
  int bos = P.bosp[0];
  for (int e = tid; e < HSZ; e += NTHR) {
    agst(&P.hd[e],        agld(&P.h1a[SEQ * HSZ + e]));
    agst(&P.cd[e],        agld(&P.c1a[SEQ * HSZ + e]));
    agst(&P.hd[1536 + e], agld(&P.h2a[SEQ * HSZ + e]));
    agst(&P.cd[1536 + e], agld(&P.c2a[SEQ * HSZ + e]));
    agst(&P.x_dec[e],     P.emb_dec[(size_t)bos * HSZ + e]);
  }
}

// ---------------- decoder phases ----------------

// one (row, gate) per wave across all 256 blocks x 8 waves = 2048 waves = 512 rows x 4 gates
template <int B>
__device__ void phase_dcell(const Ptrs& P, float* sm,
                            const float* __restrict__ Wih, const float* __restrict__ Whh,
                            const float* __restrict__ bias, const float* x,
                            const float* hin, const float* cin,
                            float* hout, float* cout, int blk, int tid) {
  float* xl = sm;
  float* hl = sm + B * HSZ;
  float* cl = sm + 2 * B * HSZ;
  float* zl = sm + 3 * B * HSZ;  // [2][4][B]
  for (int i = tid; i < B * HSZ; i += NTHR) {
    xl[i] = agld(&x[i]); hl[i] = agld(&hin[i]); cl[i] = agld(&cin[i]);
  }
  __syncthreads();
  int wave = tid >> 6, lane = tid & 63;
  int lr = wave >> 2;          // 0..1
  int g  = wave & 3;           // gate
  int j  = blk * 2 + lr;       // row 0..511
  int row = j + (g << 9);
  const float4* wi = (const float4*)(Wih + (size_t)row * HSZ);
  const float4* wh = (const float4*)(Whh + (size_t)row * HSZ);
  float4 wi0 = wi[lane], wi1 = wi[lane + 64], wh0 = wh[lane], wh1 = wh[lane + 64];
  float bb = bias[row];
#pragma unroll
  for (int b = 0; b < B; ++b) {
    float4 xv0 = ((const float4*)(xl + b * HSZ))[lane];
    float4 xv1 = ((const float4*)(xl + b * HSZ))[lane + 64];
    float4 hv0 = ((const float4*)(hl + b * HSZ))[lane];
    float4 hv1 = ((const float4*)(hl + b * HSZ))[lane + 64];
    float acc = dot4(wi0, xv0) + dot4(wi1, xv1) + dot4(wh0, hv0) + dot4(wh1, hv1);
    float z = wsum(acc) + bb;
    if (lane == 0) zl[(lr * 4 + g) * B + b] = z;
  }
  __syncthreads();
  for (int q = tid; q < 2 * B; q += NTHR) {
    int lr2 = q / B, b = q % B;
    int j2 = blk * 2 + lr2;
    float z0 = zl[(lr2 * 4 + 0) * B + b], z1 = zl[(lr2 * 4 + 1) * B + b];
    float z2 = zl[(lr2 * 4 + 2) * B + b], z3 = zl[(lr2 * 4 + 3) * B + b];
    float c = sigf(z1) * cl[b * HSZ + j2] + sigf(z0) * tanhf(z2);
    agst(&cout[b * HSZ + j2], c);
    agst(&hout[b * HSZ + j2], sigf(z3) * tanhf(c));
  }
}

// attention + context + feat; blocks 0..63 (8 waves x 64 = 512 feat rows)
template <int B>
__device__ void phase_attfeat(const Ptrs& P, float* sm, int blk, int tid) {
  if (blk >= 64) return;  // block-uniform
  float* xs  = sm;            // B*HSZ
  float* at  = sm + 1536;     // B*SEQ
  float* xcs = sm + 1728;     // B*1024
  for (int i = tid; i < B * HSZ; i += NTHR) xs[i] = agld(&P.hdn[1536 + i]);
  __syncthreads();
  if (tid < B * SEQ) {
    int b = tid >> 6, s2 = tid & 63;
    const float* er = P.h2a + (s2 + 1) * HSZ;
    const float* xb = xs + b * HSZ;
    float acc = 0.f;
    for (int e = 0; e < HSZ; e += 4) {
      float4 ev = *(const float4*)(er + e);
      acc += ev.x * xb[e] + ev.y * xb[e + 1] + ev.z * xb[e + 2] + ev.w * xb[e + 3];
    }
    at[tid] = acc;
  }
  __syncthreads();
  if (tid < B) {
    float m = -INFINITY;
    for (int s2 = 0; s2 < SEQ; ++s2) m = fmaxf(m, at[tid * SEQ + s2]);
    float s = 0.f;
    for (int s2 = 0; s2 < SEQ; ++s2) { float e = expf(at[tid * SEQ + s2] - m); at[tid * SEQ + s2] = e; s += e; }
    float inv = 1.f / s;
    for (int s2 = 0; s2 < SEQ; ++s2) at[tid * SEQ + s2] *= inv;
  }
  __syncthreads();
  if (tid < 128) {
    int h4 = tid * 4;
    float4 acc[B];
#pragma unroll
    for (int b = 0; b < B; ++b) acc[b] = make_float4(0.f, 0.f, 0.f, 0.f);
    for (int s2 = 0; s2 < SEQ; ++s2) {
      float4 ev = *(const float4*)(P.h2a + (s2 + 1) * HSZ + h4);
#pragma unroll
      for (int b = 0; b < B; ++b) {
        float a = at[b * SEQ + s2];
        acc[b].x += a * ev.x; acc[b].y += a * ev.y; acc[b].z += a * ev.z; acc[b].w += a * ev.w;
      }
    }
#pragma unroll
    for (int b = 0; b < B; ++b) *(float4*)(xcs + b * 1024 + 512 + h4) = acc[b];
  }
  for (int i = tid; i < B * HSZ; i += NTHR) {
    int b = i >> 9, hcol = i & 511;
    xcs[b * 1024 + hcol] = xs[b * HSZ + hcol];
  }
  __syncthreads();
  int wave = tid >> 6, lane = tid & 63;
  int j = blk * 8 + wave;  // 0..511
  const float4* w = (const float4*)(P.W_c + (size_t)j * 1024);
  float4 w0 = w[lane], w1 = w[lane + 64], w2 = w[lane + 128], w3 = w[lane + 192];
#pragma unroll
  for (int b = 0; b < B; ++b) {
    const float4* xb = (const float4*)(xcs + b * 1024);
    float acc = dot4(w0, xb[lane]) + dot4(w1, xb[lane + 64]) +
                dot4(w2, xb[lane + 128]) + dot4(w3, xb[lane + 192]);
    acc = wsum(acc);
    if (lane == 0) agst(&P.feat[b * HSZ + j], tanhf(acc));
  }
}

// logits + streaming (max, sumexp, top3); 2048 wave-slots, 16 rows each, 4-row batched loads
template <int B>
__device__ void phase_logits(const Ptrs& P, float* sm, int blk, int tid) {
  float* fst = sm;  // B*HSZ
  for (int i = tid; i < B * HSZ; i += NTHR) fst[i] = agld(&P.feat[i]);
  __syncthreads();
  int wave = tid >> 6, lane = tid & 63;
  int gid  = blk * 8 + wave;  // 0..2047
  float4 f0[B], f1[B];
#pragma unroll
  for (int b = 0; b < B; ++b) {
    f0[b] = ((const float4*)(fst + b * HSZ))[lane];
    f1[b] = ((const float4*)(fst + b * HSZ))[lane + 64];
  }
  float m[B], ss[B], tv[B][3];
  int tix[B][3];
#pragma unroll
  for (int b = 0; b < B; ++b) {
    m[b] = -INFINITY; ss[b] = 0.f;
#pragma unroll
    for (int k = 0; k < 3; ++k) { tv[b][k] = -INFINITY; tix[b][k] = 0x7fffffff; }
  }
  for (int k0 = 0; k0 < 16; k0 += 4) {
    float4 a0[4], a1[4]; float ab[4]; int vr[4];
#pragma unroll
    for (int u = 0; u < 4; ++u) {
      int v = gid + (k0 + u) * 2048;
      vr[u] = v;
      if (v < VOC) {
        const float4* wr = (const float4*)(P.W_out + (size_t)v * HSZ);
        a0[u] = wr[lane]; a1[u] = wr[lane + 64]; ab[u] = P.b_out[v];
      } else {
        a0[u] = make_float4(0.f, 0.f, 0.f, 0.f); a1[u] = a0[u]; ab[u] = 0.f;
      }
    }
#pragma unroll
    for (int u = 0; u < 4; ++u) {
      if (vr[u] >= VOC) continue;  // wave-uniform
#pragma unroll
      for (int b = 0; b < B; ++b) {
        float acc = wsum(dot4(a0[u], f0[b]) + dot4(a1[u], f1[b])) + ab[u];
        float mo = m[b], mn = fmaxf(mo, acc);
        ss[b] = ss[b] * expf(mo - mn) + expf(acc - mn);
        m[b]  = mn;
        ins3(tv[b], tix[b], acc, vr[u]);
      }
    }
  }
  __shared__ float lm[8][3], lss[8][3], lv[8][3][3];
  __shared__ int li[8][3][3];
  if (lane == 0) {
#pragma unroll
    for (int b = 0; b < B; ++b) {
      lm[wave][b] = m[b]; lss[wave][b] = ss[b];
#pragma unroll
      for (int k = 0; k < 3; ++k) { lv[wave][b][k] = tv[b][k]; li[wave][b][k] = tix[b][k]; }
    }
  }
  __syncthreads();
  if (tid < B) {
    int b = tid;
    float M = -INFINITY;
#pragma unroll
    for (int w2 = 0; w2 < 8; ++w2) M = fmaxf(M, lm[w2][b]);
    float S = 0.f;
#pragma unroll
    for (int w2 = 0; w2 < 8; ++w2) S += lss[w2][b] * expf(lm[w2][b] - M);
    float bv[3] = {-INFINITY, -INFINITY, -INFINITY};
    int bi3[3]  = {0x7fffffff, 0x7fffffff, 0x7fffffff};
#pragma unroll
    for (int w2 = 0; w2 < 8; ++w2)
#pragma unroll
      for (int k = 0; k < 3; ++k) ins3(bv, bi3, lv[w2][b][k], li[w2][b][k]);
    int o = blk * 3 + b;
    agst(&P.pm[o], M); agst(&P.ps[o], S);
#pragma unroll
    for (int k = 0; k < 3; ++k) {
      agst(&P.pv[o * 3 + k], bv[k]);
      __hip_atomic_store(&P.pi[o * 3 + k], bi3[k], __ATOMIC_RELAXED, __HIP_MEMORY_SCOPE_AGENT);
    }
  }
}

// final merge + beam bookkeeping; block 0, between all-to-all sync and its bar0 epoch
template <int B, int STEP0>
__device__ void merge_body(const Ptrs& P, int tid, int ti) {
  __shared__ float sM[3], sS[3], sV[3][3], sScore[3];
  __shared__ int sI[3][3], sOrig[3], sTokNew[3], sTokOld[3], sKstar;
  int wave = tid >> 6, lane = tid & 63;
  if (wave < B) {
    int b = wave;
    float lm4[4], ls4[4];
    float M = -INFINITY;
#pragma unroll
    for (int q = 0; q < 4; ++q) {
      int blk2 = lane + q * 64;
      lm4[q] = agld(&P.pm[blk2 * 3 + b]); ls4[q] = agld(&P.ps[blk2 * 3 + b]);
      M = fmaxf(M, lm4[q]);
    }
#pragma unroll
    for (int off = 32; off; off >>= 1) M = fmaxf(M, __shfl_xor(M, off, 64));
    float S = 0.f;
#pragma unroll
    for (int q = 0; q < 4; ++q) S += ls4[q] * expf(lm4[q] - M);
    S = wsum(S);
    float bv[3] = {-INFINITY, -INFINITY, -INFINITY};
    int bi3[3]  = {0x7fffffff, 0x7fffffff, 0x7fffffff};
#pragma unroll
    for (int q = 0; q < 4; ++q) {
      int blk2 = lane + q * 64;
#pragma unroll
      for (int k = 0; k < 3; ++k)
        ins3(bv, bi3, agld(&P.pv[(blk2 * 3 + b) * 3 + k]), agldi(&P.pi[(blk2 * 3 + b) * 3 + k]));
    }
#pragma unroll
    for (int off = 32; off; off >>= 1) {
      float ov[3]; int oi[3];
#pragma unroll
      for (int k = 0; k < 3; ++k) { ov[k] = __shfl_xor(bv[k], off, 64); oi[k] = __shfl_xor(bi3[k], off, 64); }
#pragma unroll
      for (int k = 0; k < 3; ++k) ins3(bv, bi3, ov[k], oi[k]);
    }
    if (lane == 0) {
      sM[b] = M; sS[b] = S;
#pragma unroll
      for (int k = 0; k < 3; ++k) { sV[b][k] = bv[k]; sI[b][k] = bi3[k]; }
    }
  }
  __syncthreads();
  if (tid == 0) {
    if (STEP0) {
      float off0 = -sM[0] - logf(sS[0]);
      for (int k = 0; k < 3; ++k) {
        sScore[k] = sV[0][k] + off0;
        sTokNew[k] = sI[0][k]; sOrig[k] = 0; sTokOld[k] = 0;
        P.scores[k] = sScore[k]; P.tokens[k] = sTokNew[k];
      }
    } else {
      float osc[3]; int otk[3];
      for (int b = 0; b < 3; ++b) { osc[b] = P.scores[b]; otk[b] = P.tokens[b]; sTokOld[b] = otk[b]; }
      float cum[9];
      for (int b = 0; b < 3; ++b) {
        float o = osc[b] - sM[b] - logf(sS[b]);
        for (int k = 0; k < 3; ++k) cum[b * 3 + k] = sV[b][k] + o;
      }
      bool used[9] = {false, false, false, false, false, false, false, false, false};
      for (int k = 0; k < 3; ++k) {
        int bf = 0; float bb = -INFINITY;
        for (int f = 0; f < 9; ++f)
          if (!used[f] && cum[f] > bb) { bb = cum[f]; bf = f; }  // strict > keeps lowest flat idx
        used[bf] = true;
        sScore[k] = bb;
        int ob = bf / 3;
        sOrig[k] = ob;
        sTokNew[k] = sI[ob][bf - ob * 3];
      }
      for (int k = 0; k < 3; ++k) { P.scores[k] = sScore[k]; P.tokens[k] = sTokNew[k]; }
    }
    float bb = -INFINITY; int kk = 0;
    for (int k = 0; k < 3; ++k) if (sScore[k] > bb) { bb = sScore[k]; kk = k; }
    sKstar = kk;
  }
  __syncthreads();
  for (int idx = tid; idx < 2 * 3 * HSZ; idx += NTHR) {
    int l = idx / 1536, rem = idx % 1536, k = rem / HSZ, e = rem & 511;
    int o = STEP0 ? 0 : sOrig[k];
    agst(&P.hd[l * 1536 + k * HSZ + e], agld(&P.hdn[l * 1536 + o * HSZ + e]));
    agst(&P.cd[l * 1536 + k * HSZ + e], agld(&P.cdn[l * 1536 + o * HSZ + e]));
  }
  if (STEP0) {
    int bos = P.bosp[0];
    for (int idx = tid; idx < BEAM * TMAX; idx += NTHR) P.bt[idx] = bos;  // buffer 0
  } else {
    const int* src = P.bt + (ti & 1) * (BEAM * TMAX);
    int* dst = P.bt + ((ti + 1) & 1) * (BEAM * TMAX);
    for (int idx = tid; idx < BEAM * TMAX; idx += NTHR) {
      int k = idx / TMAX, jj = idx % TMAX, o = sOrig[k];
      dst[idx] = (jj == ti + 1) ? sTokOld[o] : src[o * TMAX + jj];
    }
  }
  for (int idx = tid; idx < BEAM * HSZ; idx += NTHR) {
    int k = idx >> 9, e = idx & 511;
    agst(&P.x_dec[idx], P.emb_dec[(size_t)sTokNew[k] * HSZ + e]);
  }
  if (!STEP0 && ti == TMAX - 2) {
    __syncthreads();
    const int* dst = P.bt + ((ti + 1) & 1) * (BEAM * TMAX);
    for (int jj = tid; jj < TMAX; jj += NTHR) P.outp[jj] = dst[sKstar * TMAX + jj];
  }
}

template <int B, int STEP0>
__device__ void dstep(const Ptrs& P, float* sm, int blk, int tid, int& nb, int ti) {
  phase_dcell<B>(P, sm, P.Wih_dec, P.Whh_dec, P.b_dec, P.x_dec, P.hd, P.cd, P.hdn, P.cdn, blk, tid);
  gbar_all(P.flags, blk, tid, ++nb);
  phase_dcell<B>(P, sm, P.Wih_dec + LOFF, P.Whh_dec + LOFF, P.b_dec + H4,
                 P.hdn, P.hd + 1536, P.cd + 1536, P.hdn + 1536, P.cdn + 1536, blk, tid);
  gbar_all(P.flags, blk, tid, ++nb);
  phase_attfeat<B>(P, sm, blk, tid);
  gbar_all(P.flags, blk, tid, ++nb);
  phase_logits<B>(P, sm, blk, tid);
  gbar_all(P.flags, blk, tid, ++nb);   // all partials globally visible
  if (blk == 0) merge_body<B, STEP0>(P, tid, ti);
  bar0(P.flags, blk, tid, ++nb);       // block0 publishes merge completion
}

__global__ void __launch_bounds__(NTHR) mega(Ptrs P) {
  __shared__ float sm[4832];  // shared arena, reused by all phases
  int blk = blockIdx.x, tid = threadIdx.x;
  int nb = 0;

  phase_xw1(P, blk, tid);
  gbar_all(P.flags, blk, tid, ++nb);
  for (int s = 0; s <= SEQ; ++s) {
    phase_encslot(P, sm, blk, tid, s);
    gbar_all(P.flags, blk, tid, ++nb);
  }
  if (blk == 0) dinit_body(P, tid);
  bar0(P.flags, blk, tid, ++nb);

  for (int step = 0; step < TMAX; ++step) {
    if (step == 0) dstep<1, 1>(P, sm, blk, tid, nb, -1);
    else           dstep<3, 0>(P, sm, blk, tid, nb, step - 1);
  }
}

extern "C" void kernel_launch(void* const* d_in, const int* in_sizes, int n_in,
                              void* d_out, int out_size, void* d_ws, size_t ws_size,
                              hipStream_t stream) {
  Ptrs P;
  P.seq     = (const int*)d_in[0];
  P.emb_enc = (const float*)d_in[1];
  P.Wih_enc = (const float*)d_in[2];
  P.Whh_enc = (const float*)d_in[3];
  P.b_enc   = (const float*)d_in[4];
  P.emb_dec = (const float*)d_in[5];
  P.Wih_dec = (const float*)d_in[6];
  P.Whh_dec = (const float*)d_in[7];
  P.b_dec   = (const float*)d_in[8];
  P.W_c     = (const float*)d_in[9];
  P.W_out   = (const float*)d_in[10];
  P.b_out   = (const float*)d_in[11];
  P.bosp    = (const int*)d_in[14];

  // barrier region: 256 flag lines (64 B each), zeroed every call
  P.flags = (int*)d_ws;

  float* w = (float*)d_ws + NBLK * FLS;
  P.xp1     = w; w += SEQ * H4;
  P.h1a     = w; w += (SEQ + 1) * HSZ;
  P.c1a     = w; w += (SEQ + 1) * HSZ;
  P.h2a     = w; w += (SEQ + 1) * HSZ;
  P.c2a     = w; w += (SEQ + 1) * HSZ;
  P.hd      = w; w += 2 * BEAM * HSZ;
  P.cd      = w; w += 2 * BEAM * HSZ;
  P.hdn     = w; w += 2 * BEAM * HSZ;
  P.cdn     = w; w += 2 * BEAM * HSZ;
  P.x_dec   = w; w += BEAM * HSZ;
  P.feat    = w; w += BEAM * HSZ;
  P.pm      = w; w += NBLK * 3;
  P.ps      = w; w += NBLK * 3;
  P.pv      = w; w += NBLK * 3 * 3;
  P.scores  = w; w += 4;
  P.pi      = (int*)w; w += NBLK * 3 * 3;
  P.tokens  = (int*)w; w += 4;
  P.bt      = (int*)w; w += 2 * BEAM * TMAX + 4;
  P.outp    = (int*)d_out;

  hipMemsetAsync(d_ws, 0, NBLK * FLS * sizeof(int), stream);
  mega<<<dim3(NBLK), dim3(NTHR), 0, stream>>>(P);
}

// Round 9
// 3896.611 us; speedup vs baseline: 1.1681x; 1.1681x over previous
//
#include <hip/hip_runtime.h>
#include <math.h>

// Problem constants (fixed by the reference module)
#define HSZ   512
#define H4    2048
#define SEQ   64
#define VOC   32000
#define BEAM  3
#define TMAX  50

#define LOFF  ((size_t)H4 * HSZ)   // per-layer weight stride

__device__ __forceinline__ float wsum(float v) {
#pragma unroll
  for (int off = 32; off; off >>= 1) v += __shfl_xor(v, off, 64);
  return v;
}
__device__ __forceinline__ float dot4(float4 a, float4 b) {
  return a.x * b.x + a.y * b.y + a.z * b.z + a.w * b.w;
}
__device__ __forceinline__ float sigf(float x) { return 1.f / (1.f + expf(-x)); }

__device__ __forceinline__ bool better(float v1, int i1, float v2, int i2) {
  return (v1 > v2) || (v1 == v2 && i1 < i2);  // jax.lax.top_k order: value desc, index asc
}
__device__ __forceinline__ void ins3(float* v, int* idx, float nv, int ni) {
  if (better(nv, ni, v[2], idx[2])) {
    if (better(nv, ni, v[1], idx[1])) {
      v[2] = v[1]; idx[2] = idx[1];
      if (better(nv, ni, v[0], idx[0])) { v[1] = v[0]; idx[1] = idx[0]; v[0] = nv; idx[0] = ni; }
      else { v[1] = nv; idx[1] = ni; }
    } else { v[2] = nv; idx[2] = ni; }
  }
}

// ---------------- encoder ----------------

// xp1[t][r] = b_enc[r] + dot(Wih_enc[r], emb_enc[seq[t]]); wave owns row r, lane owns t
__global__ void __launch_bounds__(512) k_xw1(const float* __restrict__ Wih,
                                             const float* __restrict__ bias,
                                             const float* __restrict__ emb,
                                             const int* __restrict__ seq,
                                             float* __restrict__ xp1) {
  int t    = threadIdx.x & 63;
  int wave = threadIdx.x >> 6;
  int r    = blockIdx.x * 8 + wave;
  int tok  = seq[t];
  const float* xr = emb + (size_t)tok * HSZ;
  const float* wr = Wih + (size_t)r * HSZ;
  float acc = 0.f;
  for (int e = 0; e < HSZ; e += 4) {
    float4 wv = *(const float4*)(wr + e);
    float4 xv = *(const float4*)(xr + e);
    acc += dot4(wv, xv);
  }
  xp1[t * H4 + r] = acc + bias[r];
}

// One wavefront slot: layer1 cell t=s (blocks 0..127), layer2 cell t=s-1 (blocks 128..255).
// 4 rows/block, 2 gates/wave; gates recombined in LDS. Per-gate math identical to r7/r8.
__global__ void __launch_bounds__(512) k_encslot(const float* __restrict__ Whh1,
                                                 const float* __restrict__ Wih2,
                                                 const float* __restrict__ Whh2,
                                                 const float* __restrict__ b2,
                                                 const float* __restrict__ xp1,
                                                 float* __restrict__ h1a, float* __restrict__ c1a,
                                                 float* __restrict__ h2a, float* __restrict__ c2a,
                                                 int s) {
  __shared__ float rowX[HSZ], rowH[HSZ], zl[16];
  int tid = threadIdx.x, wave = tid >> 6, lane = tid & 63;
  bool l2 = blockIdx.x >= 128;
  int t = l2 ? s - 1 : s;
  if (t < 0 || t >= SEQ) return;
  int bb = blockIdx.x & 127;
  int lr = wave >> 1;            // 0..3 local row
  int j  = bb * 4 + lr;          // 0..511
  int g0 = (wave & 1) * 2;       // gates {g0, g0+1}
  if (!l2) {
    rowX[tid] = (t > 0) ? h1a[t * HSZ + tid] : 0.f;
    __syncthreads();
    float4 h0 = ((const float4*)rowX)[lane], h1v = ((const float4*)rowX)[lane + 64];
#pragma unroll
    for (int gg = 0; gg < 2; ++gg) {
      int g = g0 + gg;
      int row = j + (g << 9);
      const float4* wr = (const float4*)(Whh1 + (size_t)row * HSZ);
      float zs = wsum(dot4(wr[lane], h0) + dot4(wr[lane + 64], h1v));
      if (lane == 0) zl[lr * 4 + g] = zs + xp1[t * H4 + row];
    }
    __syncthreads();
    if (tid < 4) {
      int j2 = bb * 4 + tid;
      float z0 = zl[tid * 4 + 0], z1 = zl[tid * 4 + 1], z2 = zl[tid * 4 + 2], z3 = zl[tid * 4 + 3];
      float cp = (t > 0) ? c1a[t * HSZ + j2] : 0.f;
      float c = sigf(z1) * cp + sigf(z0) * tanhf(z2);
      c1a[(t + 1) * HSZ + j2] = c;
      h1a[(t + 1) * HSZ + j2] = sigf(z3) * tanhf(c);
    }
  } else {
    rowX[tid] = h1a[(t + 1) * HSZ + tid];
    rowH[tid] = (t > 0) ? h2a[t * HSZ + tid] : 0.f;
    __syncthreads();
    float4 x0 = ((const float4*)rowX)[lane], x1 = ((const float4*)rowX)[lane + 64];
    float4 h0 = ((const float4*)rowH)[lane], h1v = ((const float4*)rowH)[lane + 64];
#pragma unroll
    for (int gg = 0; gg < 2; ++gg) {
      int g = g0 + gg;
      int row = j + (g << 9);
      const float4* wi = (const float4*)(Wih2 + (size_t)row * HSZ);
      const float4* wh = (const float4*)(Whh2 + (size_t)row * HSZ);
      float zs = wsum(dot4(wi[lane], x0) + dot4(wi[lane + 64], x1) +
                      dot4(wh[lane], h0) + dot4(wh[lane + 64], h1v));
      if (lane == 0) zl[lr * 4 + g] = zs + b2[row];
    }
    __syncthreads();
    if (tid < 4) {
      int j2 = bb * 4 + tid;
      float z0 = zl[tid * 4 + 0], z1 = zl[tid * 4 + 1], z2 = zl[tid * 4 + 2], z3 = zl[tid * 4 + 3];
      float cp = (t > 0) ? c2a[t * HSZ + j2] : 0.f;
      float c = sigf(z1) * cp + sigf(z0) * tanhf(z2);
      c2a[(t + 1) * HSZ + j2] = c;
      h2a[(t + 1) * HSZ + j2] = sigf(z3) * tanhf(c);
    }
  }
}

__global__ void __launch_bounds__(512) k_dinit(const float* __restrict__ h1a,
                                               const float* __restrict__ c1a,
                                               const float* __restrict__ h2a,
                                               const float* __restrict__ c2a,
                                               float* __restrict__ hd, float* __restrict__ cd,
                                               float* __restrict__ x_dec,
                                               const float* __restrict__ emb_dec,
                                               const int* __restrict__ bosp) {
  int bos = bosp[0];
  for (int e = threadIdx.x; e < HSZ; e += 512) {
    hd[e]        = h1a[SEQ * HSZ + e];
    cd[e]        = c1a[SEQ * HSZ + e];
    hd[1536 + e] = h2a[SEQ * HSZ + e];
    cd[1536 + e] = c2a[SEQ * HSZ + e];
    x_dec[e]     = emb_dec[(size_t)bos * HSZ + e];
  }
}

// ---------------- decoder ----------------

// one (row, gate) per wave: 256 blocks x 8 waves = 2048 waves = 512 rows x 4 gates
template <int B>
__global__ void __launch_bounds__(512) k_dcell(const float* __restrict__ Wih,
                                               const float* __restrict__ Whh,
                                               const float* __restrict__ bias,
                                               const float* __restrict__ x,
                                               const float* __restrict__ hin,
                                               const float* __restrict__ cin,
                                               float* __restrict__ hout, float* __restrict__ cout) {
  __shared__ float xl[B * HSZ], hl[B * HSZ], cl[B * HSZ], zl[8 * B];
  int tid = threadIdx.x;
  for (int i = tid; i < B * HSZ; i += 512) { xl[i] = x[i]; hl[i] = hin[i]; cl[i] = cin[i]; }
  __syncthreads();
  int wave = tid >> 6, lane = tid & 63;
  int lr = wave >> 2;          // 0..1
  int g  = wave & 3;           // gate
  int j  = blockIdx.x * 2 + lr;
  int row = j + (g << 9);
  const float4* wi = (const float4*)(Wih + (size_t)row * HSZ);
  const float4* wh = (const float4*)(Whh + (size_t)row * HSZ);
  float4 wi0 = wi[lane], wi1 = wi[lane + 64], wh0 = wh[lane], wh1 = wh[lane + 64];
  float bb = bias[row];
#pragma unroll
  for (int b = 0; b < B; ++b) {
    float4 xv0 = ((const float4*)(xl + b * HSZ))[lane];
    float4 xv1 = ((const float4*)(xl + b * HSZ))[lane + 64];
    float4 hv0 = ((const float4*)(hl + b * HSZ))[lane];
    float4 hv1 = ((const float4*)(hl + b * HSZ))[lane + 64];
    float acc = dot4(wi0, xv0) + dot4(wi1, xv1) + dot4(wh0, hv0) + dot4(wh1, hv1);
    float z = wsum(acc) + bb;
    if (lane == 0) zl[(lr * 4 + g) * B + b] = z;
  }
  __syncthreads();
  for (int q = tid; q < 2 * B; q += 512) {
    int lr2 = q / B, b = q % B;
    int j2 = blockIdx.x * 2 + lr2;
    float z0 = zl[(lr2 * 4 + 0) * B + b], z1 = zl[(lr2 * 4 + 1) * B + b];
    float z2 = zl[(lr2 * 4 + 2) * B + b], z3 = zl[(lr2 * 4 + 3) * B + b];
    float c = sigf(z1) * cl[b * HSZ + j2] + sigf(z0) * tanhf(z2);
    cout[b * HSZ + j2] = c;
    hout[b * HSZ + j2] = sigf(z3) * tanhf(c);
  }
}

// attention + context + feat; 64 blocks x 512 (8 waves x 64 = 512 feat rows)
template <int B>
__global__ void __launch_bounds__(512) k_attfeat(const float* __restrict__ h2,
                                                 const float* __restrict__ enc,   // h2a
                                                 const float* __restrict__ Wc,
                                                 float* __restrict__ feat) {
  __shared__ float xs[BEAM * HSZ], at[BEAM * SEQ], xcs[BEAM * 1024];
  int tid = threadIdx.x;
  for (int i = tid; i < B * HSZ; i += 512) xs[i] = h2[i];
  __syncthreads();
  if (tid < B * SEQ) {
    int b = tid >> 6, s2 = tid & 63;
    const float* er = enc + (s2 + 1) * HSZ;
    const float* xb = xs + b * HSZ;
    float acc = 0.f;
    for (int e = 0; e < HSZ; e += 4) {
      float4 ev = *(const float4*)(er + e);
      acc += ev.x * xb[e] + ev.y * xb[e + 1] + ev.z * xb[e + 2] + ev.w * xb[e + 3];
    }
    at[tid] = acc;
  }
  __syncthreads();
  if (tid < B) {
    float m = -INFINITY;
    for (int s2 = 0; s2 < SEQ; ++s2) m = fmaxf(m, at[tid * SEQ + s2]);
    float s = 0.f;
    for (int s2 = 0; s2 < SEQ; ++s2) { float e = expf(at[tid * SEQ + s2] - m); at[tid * SEQ + s2] = e; s += e; }
    float inv = 1.f / s;
    for (int s2 = 0; s2 < SEQ; ++s2) at[tid * SEQ + s2] *= inv;
  }
  __syncthreads();
  if (tid < 128) {
    int h4 = tid * 4;
    float4 acc[B];
#pragma unroll
    for (int b = 0; b < B; ++b) acc[b] = make_float4(0.f, 0.f, 0.f, 0.f);
    for (int s2 = 0; s2 < SEQ; ++s2) {
      float4 ev = *(const float4*)(enc + (s2 + 1) * HSZ + h4);
#pragma unroll
      for (int b = 0; b < B; ++b) {
        float a = at[b * SEQ + s2];
        acc[b].x += a * ev.x; acc[b].y += a * ev.y; acc[b].z += a * ev.z; acc[b].w += a * ev.w;
      }
    }
#pragma unroll
    for (int b = 0; b < B; ++b) *(float4*)(xcs + b * 1024 + 512 + h4) = acc[b];
  }
  for (int i = tid; i < B * HSZ; i += 512) {
    int b = i >> 9, hcol = i & 511;
    xcs[b * 1024 + hcol] = xs[b * HSZ + hcol];
  }
  __syncthreads();
  int wave = tid >> 6, lane = tid & 63;
  int j = blockIdx.x * 8 + wave;  // 0..511
  const float4* w = (const float4*)(Wc + (size_t)j * 1024);
  float4 w0 = w[lane], w1 = w[lane + 64], w2 = w[lane + 128], w3 = w[lane + 192];
#pragma unroll
  for (int b = 0; b < B; ++b) {
    const float4* xb = (const float4*)(xcs + b * 1024);
    float acc = dot4(w0, xb[lane]) + dot4(w1, xb[lane + 64]) +
                dot4(w2, xb[lane + 128]) + dot4(w3, xb[lane + 192]);
    acc = wsum(acc);
    if (lane == 0) feat[b * HSZ + j] = tanhf(acc);
  }
}

// logits + streaming (max, sumexp, top3); 2048 wave-slots, 16 rows each, 8-row batched loads
// (v order within a wave strictly ascending => accumulation bit-identical to r7/r8)
template <int B>
__global__ void __launch_bounds__(512) k_logits(const float* __restrict__ Wout,
                                                const float* __restrict__ bout,
                                                const float* __restrict__ feat,
                                                float* __restrict__ pm, float* __restrict__ ps,
                                                float* __restrict__ pv, int* __restrict__ pi) {
  __shared__ float fst[BEAM * HSZ];
  int tid = threadIdx.x;
  for (int i = tid; i < B * HSZ; i += 512) fst[i] = feat[i];
  __syncthreads();
  int wave = tid >> 6, lane = tid & 63;
  int gid  = blockIdx.x * 8 + wave;  // 0..2047
  float4 f0[B], f1[B];
#pragma unroll
  for (int b = 0; b < B; ++b) {
    f0[b] = ((const float4*)(fst + b * HSZ))[lane];
    f1[b] = ((const float4*)(fst + b * HSZ))[lane + 64];
  }
  float m[B], ss[B], tv[B][3];
  int tix[B][3];
#pragma unroll
  for (int b = 0; b < B; ++b) {
    m[b] = -INFINITY; ss[b] = 0.f;
#pragma unroll
    for (int k = 0; k < 3; ++k) { tv[b][k] = -INFINITY; tix[b][k] = 0x7fffffff; }
  }
  for (int k0 = 0; k0 < 16; k0 += 8) {
    float4 a0[8], a1[8]; float ab[8]; int vr[8];
#pragma unroll
    for (int u = 0; u < 8; ++u) {
      int v = gid + (k0 + u) * 2048;
      vr[u] = v;
      if (v < VOC) {
        const float4* wr = (const float4*)(Wout + (size_t)v * HSZ);
        a0[u] = wr[lane]; a1[u] = wr[lane + 64]; ab[u] = bout[v];
      } else {
        a0[u] = make_float4(0.f, 0.f, 0.f, 0.f); a1[u] = a0[u]; ab[u] = 0.f;
      }
    }
#pragma unroll
    for (int u = 0; u < 8; ++u) {
      if (vr[u] >= VOC) continue;  // wave-uniform
#pragma unroll
      for (int b = 0; b < B; ++b) {
        float acc = wsum(dot4(a0[u], f0[b]) + dot4(a1[u], f1[b])) + ab[u];
        float mo = m[b], mn = fmaxf(mo, acc);
        ss[b] = ss[b] * expf(mo - mn) + expf(acc - mn);
        m[b]  = mn;
        ins3(tv[b], tix[b], acc, vr[u]);
      }
    }
  }
  __shared__ float lm[8][3], lss[8][3], lv[8][3][3];
  __shared__ int li[8][3][3];
  if (lane == 0) {
#pragma unroll
    for (int b = 0; b < B; ++b) {
      lm[wave][b] = m[b]; lss[wave][b] = ss[b];
#pragma unroll
      for (int k = 0; k < 3; ++k) { lv[wave][b][k] = tv[b][k]; li[wave][b][k] = tix[b][k]; }
    }
  }
  __syncthreads();
  if (tid < B) {
    int b = tid;
    float M = -INFINITY;
#pragma unroll
    for (int w2 = 0; w2 < 8; ++w2) M = fmaxf(M, lm[w2][b]);
    float S = 0.f;
#pragma unroll
    for (int w2 = 0; w2 < 8; ++w2) S += lss[w2][b] * expf(lm[w2][b] - M);
    float bv[3] = {-INFINITY, -INFINITY, -INFINITY};
    int bi3[3]  = {0x7fffffff, 0x7fffffff, 0x7fffffff};
#pragma unroll
    for (int w2 = 0; w2 < 8; ++w2)
#pragma unroll
      for (int k = 0; k < 3; ++k) ins3(bv, bi3, lv[w2][b][k], li[w2][b][k]);
    int o = blockIdx.x * 3 + b;
    pm[o] = M; ps[o] = S;
#pragma unroll
    for (int k = 0; k < 3; ++k) { pv[o * 3 + k] = bv[k]; pi[o * 3 + k] = bi3[k]; }
  }
}

// final merge + beam bookkeeping; 1 block x 256
template <int B, int STEP0>
__global__ void __launch_bounds__(256) k_merge(const float* __restrict__ pm,
                                               const float* __restrict__ ps,
                                               const float* __restrict__ pv,
                                               const int* __restrict__ pi,
                                               const float* __restrict__ hdn,
                                               const float* __restrict__ cdn,
                                               float* __restrict__ hd, float* __restrict__ cd,
                                               int* __restrict__ bt, float* __restrict__ scores,
                                               int* __restrict__ tokens, float* __restrict__ x_dec,
                                               const float* __restrict__ emb_dec,
                                               const int* __restrict__ bosp,
                                               int* __restrict__ outp, int ti) {
  __shared__ float sM[3], sS[3], sV[3][3], sScore[3];
  __shared__ int sI[3][3], sOrig[3], sTokNew[3], sTokOld[3], sKstar;
  int tid = threadIdx.x, wave = tid >> 6, lane = tid & 63;
  if (wave < B) {
    int b = wave;
    float lm4[4], ls4[4];
    float M = -INFINITY;
#pragma unroll
    for (int q = 0; q < 4; ++q) {
      int blk2 = lane + q * 64;
      lm4[q] = pm[blk2 * 3 + b]; ls4[q] = ps[blk2 * 3 + b];
      M = fmaxf(M, lm4[q]);
    }
#pragma unroll
    for (int off = 32; off; off >>= 1) M = fmaxf(M, __shfl_xor(M, off, 64));
    float S = 0.f;
#pragma unroll
    for (int q = 0; q < 4; ++q) S += ls4[q] * expf(lm4[q] - M);
    S = wsum(S);
    float bv[3] = {-INFINITY, -INFINITY, -INFINITY};
    int bi3[3]  = {0x7fffffff, 0x7fffffff, 0x7fffffff};
#pragma unroll
    for (int q = 0; q < 4; ++q) {
      int blk2 = lane + q * 64;
#pragma unroll
      for (int k = 0; k < 3; ++k)
        ins3(bv, bi3, pv[(blk2 * 3 + b) * 3 + k], pi[(blk2 * 3 + b) * 3 + k]);
    }
#pragma unroll
    for (int off = 32; off; off >>= 1) {
      float ov[3]; int oi[3];
#pragma unroll
      for (int k = 0; k < 3; ++k) { ov[k] = __shfl_xor(bv[k], off, 64); oi[k] = __shfl_xor(bi3[k], off, 64); }
#pragma unroll
      for (int k = 0; k < 3; ++k) ins3(bv, bi3, ov[k], oi[k]);
    }
    if (lane == 0) {
      sM[b] = M; sS[b] = S;
#pragma unroll
      for (int k = 0; k < 3; ++k) { sV[b][k] = bv[k]; sI[b][k] = bi3[k]; }
    }
  }
  __syncthreads();
  if (tid == 0) {
    if (STEP0) {
      float off0 = -sM[0] - logf(sS[0]);
      for (int k = 0; k < 3; ++k) {
        sScore[k] = sV[0][k] + off0;
        sTokNew[k] = sI[0][k]; sOrig[k] = 0; sTokOld[k] = 0;
        scores[k] = sScore[k]; tokens[k] = sTokNew[k];
      }
    } else {
      float osc[3]; int otk[3];
      for (int b = 0; b < 3; ++b) { osc[b] = scores[b]; otk[b] = tokens[b]; sTokOld[b] = otk[b]; }
      float cum[9];
      for (int b = 0; b < 3; ++b) {
        float o = osc[b] - sM[b] - logf(sS[b]);
        for (int k = 0; k < 3; ++k) cum[b * 3 + k] = sV[b][k] + o;
      }
      bool used[9] = {false, false, false, false, false, false, false, false, false};
      for (int k = 0; k < 3; ++k) {
        int bf = 0; float bb = -INFINITY;
        for (int f = 0; f < 9; ++f)
          if (!used[f] && cum[f] > bb) { bb = cum[f]; bf = f; }  // strict > keeps lowest flat idx
        used[bf] = true;
        sScore[k] = bb;
        int ob = bf / 3;
        sOrig[k] = ob;
        sTokNew[k] = sI[ob][bf - ob * 3];
      }
      for (int k = 0; k < 3; ++k) { scores[k] = sScore[k]; tokens[k] = sTokNew[k]; }
    }
    float bb = -INFINITY; int kk = 0;
    for (int k = 0; k < 3; ++k) if (sScore[k] > bb) { bb = sScore[k]; kk = k; }
    sKstar = kk;
  }
  __syncthreads();
  for (int idx = tid; idx < 2 * 3 * HSZ; idx += 256) {
    int l = idx / 1536, rem = idx % 1536, k = rem / HSZ, e = rem & 511;
    int o = STEP0 ? 0 : sOrig[k];
    hd[l * 1536 + k * HSZ + e] = hdn[l * 1536 + o * HSZ + e];
    cd[l * 1536 + k * HSZ + e] = cdn[l * 1536 + o * HSZ + e];
  }
  if (STEP0) {
    int bos = bosp[0];
    for (int idx = tid; idx < BEAM * TMAX; idx += 256) bt[idx] = bos;  // buffer 0
  } else {
    const int* src = bt + (ti & 1) * (BEAM * TMAX);
    int* dst = bt + ((ti + 1) & 1) * (BEAM * TMAX);
    for (int idx = tid; idx < BEAM * TMAX; idx += 256) {
      int k = idx / TMAX, jj = idx % TMAX, o = sOrig[k];
      dst[idx] = (jj == ti + 1) ? sTokOld[o] : src[o * TMAX + jj];
    }
  }
  for (int idx = tid; idx < BEAM * HSZ; idx += 256) {
    int k = idx >> 9, e = idx & 511;
    x_dec[idx] = emb_dec[(size_t)sTokNew[k] * HSZ + e];
  }
  if (!STEP0 && ti == TMAX - 2) {
    __syncthreads();
    const int* dst = bt + ((ti + 1) & 1) * (BEAM * TMAX);
    for (int jj = tid; jj < TMAX; jj += 256) outp[jj] = dst[sKstar * TMAX + jj];
  }
}

extern "C" void kernel_launch(void* const* d_in, const int* in_sizes, int n_in,
                              void* d_out, int out_size, void* d_ws, size_t ws_size,
                              hipStream_t stream) {
  const int*   seq     = (const int*)d_in[0];
  const float* emb_enc = (const float*)d_in[1];
  const float* Wih_enc = (const float*)d_in[2];
  const float* Whh_enc = (const float*)d_in[3];
  const float* b_enc   = (const float*)d_in[4];
  const float* emb_dec = (const float*)d_in[5];
  const float* Wih_dec = (const float*)d_in[6];
  const float* Whh_dec = (const float*)d_in[7];
  const float* b_dec   = (const float*)d_in[8];
  const float* W_c     = (const float*)d_in[9];
  const float* W_out   = (const float*)d_in[10];
  const float* b_out   = (const float*)d_in[11];
  const int*   bosp    = (const int*)d_in[14];

  float* w = (float*)d_ws;
  float* xp1     = w; w += SEQ * H4;
  float* h1a     = w; w += (SEQ + 1) * HSZ;
  float* c1a     = w; w += (SEQ + 1) * HSZ;
  float* h2a     = w; w += (SEQ + 1) * HSZ;
  float* c2a     = w; w += (SEQ + 1) * HSZ;
  float* hd      = w; w += 2 * BEAM * HSZ;
  float* cd      = w; w += 2 * BEAM * HSZ;
  float* hdn     = w; w += 2 * BEAM * HSZ;
  float* cdn     = w; w += 2 * BEAM * HSZ;
  float* x_dec   = w; w += BEAM * HSZ;
  float* feat    = w; w += BEAM * HSZ;
  float* pm      = w; w += 256 * 3;
  float* ps      = w; w += 256 * 3;
  float* pv      = w; w += 256 * 3 * 3;
  float* scores  = w; w += 4;
  int* pi     = (int*)w; w += 256 * 3 * 3;
  int* tokens = (int*)w; w += 4;
  int* bt     = (int*)w; w += 2 * BEAM * TMAX + 4;
  int* outp   = (int*)d_out;

  k_xw1<<<256, 512, 0, stream>>>(Wih_enc, b_enc, emb_enc, seq, xp1);
  for (int s = 0; s <= SEQ; ++s)
    k_encslot<<<256, 512, 0, stream>>>(Whh_enc, Wih_enc + LOFF, Whh_enc + LOFF, b_enc + H4,
                                       xp1, h1a, c1a, h2a, c2a, s);
  k_dinit<<<1, 512, 0, stream>>>(h1a, c1a, h2a, c2a, hd, cd, x_dec, emb_dec, bosp);

  for (int step = 0; step < TMAX; ++step) {
    int ti = step - 1;
    if (step == 0) {
      k_dcell<1><<<256, 512, 0, stream>>>(Wih_dec, Whh_dec, b_dec, x_dec, hd, cd, hdn, cdn);
      k_dcell<1><<<256, 512, 0, stream>>>(Wih_dec + LOFF, Whh_dec + LOFF, b_dec + H4,
                                          hdn, hd + 1536, cd + 1536, hdn + 1536, cdn + 1536);
      k_attfeat<1><<<64, 512, 0, stream>>>(hdn + 1536, h2a, W_c, feat);
      k_logits<1><<<256, 512, 0, stream>>>(W_out, b_out, feat, pm, ps, pv, pi);
      k_merge<1, 1><<<1, 256, 0, stream>>>(pm, ps, pv, pi, hdn, cdn, hd, cd, bt, scores,
                                           tokens, x_dec, emb_dec, bosp, outp, ti);
    } else {
      k_dcell<3><<<256, 512, 0, stream>>>(Wih_dec, Whh_dec, b_dec, x_dec, hd, cd, hdn, cdn);
      k_dcell<3><<<256, 512, 0, stream>>>(Wih_dec + LOFF, Whh_dec + LOFF, b_dec + H4,
                                          hdn, hd + 1536, cd + 1536, hdn + 1536, cdn + 1536);
      k_attfeat<3><<<64, 512, 0, stream>>>(hdn + 1536, h2a, W_c, feat);
      k_logits<3><<<256, 512, 0, stream>>>(W_out, b_out, feat, pm, ps, pv, pi);
      k_merge<3, 0><<<1, 256, 0, stream>>>(pm, ps, pv, pi, hdn, cdn, hd, cd, bt, scores,
                                           tokens, x_dec, emb_dec, bosp, outp, ti);
    }
  }
}

// Round 10
// 3594.693 us; speedup vs baseline: 1.2662x; 1.0840x over previous
//
#include <hip/hip_runtime.h>
#include <math.h>

// Problem constants (fixed by the reference module)
#define HSZ   512
#define H4    2048
#define SEQ   64
#define VOC   32000
#define BEAM  3
#define TMAX  50

#define LOFF  ((size_t)H4 * HSZ)   // per-layer weight stride

__device__ __forceinline__ float wsum(float v) {
#pragma unroll
  for (int off = 32; off; off >>= 1) v += __shfl_xor(v, off, 64);
  return v;
}
__device__ __forceinline__ float dot4(float4 a, float4 b) {
  return a.x * b.x + a.y * b.y + a.z * b.z + a.w * b.w;
}
__device__ __forceinline__ float sigf(float x) { return 1.f / (1.f + expf(-x)); }

__device__ __forceinline__ bool better(float v1, int i1, float v2, int i2) {
  return (v1 > v2) || (v1 == v2 && i1 < i2);  // jax.lax.top_k order: value desc, index asc
}
__device__ __forceinline__ void ins3(float* v, int* idx, float nv, int ni) {
  if (better(nv, ni, v[2], idx[2])) {
    if (better(nv, ni, v[1], idx[1])) {
      v[2] = v[1]; idx[2] = idx[1];
      if (better(nv, ni, v[0], idx[0])) { v[1] = v[0]; idx[1] = idx[0]; v[0] = nv; idx[0] = ni; }
      else { v[1] = nv; idx[1] = ni; }
    } else { v[2] = nv; idx[2] = ni; }
  }
}

// ---------------- encoder ----------------

__global__ void __launch_bounds__(512) k_xw1(const float* __restrict__ Wih,
                                             const float* __restrict__ bias,
                                             const float* __restrict__ emb,
                                             const int* __restrict__ seq,
                                             float* __restrict__ xp1) {
  int t    = threadIdx.x & 63;
  int wave = threadIdx.x >> 6;
  int r    = blockIdx.x * 8 + wave;
  int tok  = seq[t];
  const float* xr = emb + (size_t)tok * HSZ;
  const float* wr = Wih + (size_t)r * HSZ;
  float acc = 0.f;
  for (int e = 0; e < HSZ; e += 4) {
    float4 wv = *(const float4*)(wr + e);
    float4 xv = *(const float4*)(xr + e);
    acc += dot4(wv, xv);
  }
  xp1[t * H4 + r] = acc + bias[r];
}

__global__ void __launch_bounds__(512) k_encslot(const float* __restrict__ Whh1,
                                                 const float* __restrict__ Wih2,
                                                 const float* __restrict__ Whh2,
                                                 const float* __restrict__ b2,
                                                 const float* __restrict__ xp1,
                                                 float* __restrict__ h1a, float* __restrict__ c1a,
                                                 float* __restrict__ h2a, float* __restrict__ c2a,
                                                 int s) {
  __shared__ float rowX[HSZ], rowH[HSZ], zl[16];
  int tid = threadIdx.x, wave = tid >> 6, lane = tid & 63;
  bool l2 = blockIdx.x >= 128;
  int t = l2 ? s - 1 : s;
  if (t < 0 || t >= SEQ) return;
  int bb = blockIdx.x & 127;
  int lr = wave >> 1;
  int j  = bb * 4 + lr;
  int g0 = (wave & 1) * 2;
  if (!l2) {
    rowX[tid] = (t > 0) ? h1a[t * HSZ + tid] : 0.f;
    __syncthreads();
    float4 h0 = ((const float4*)rowX)[lane], h1v = ((const float4*)rowX)[lane + 64];
#pragma unroll
    for (int gg = 0; gg < 2; ++gg) {
      int g = g0 + gg;
      int row = j + (g << 9);
      const float4* wr = (const float4*)(Whh1 + (size_t)row * HSZ);
      float zs = wsum(dot4(wr[lane], h0) + dot4(wr[lane + 64], h1v));
      if (lane == 0) zl[lr * 4 + g] = zs + xp1[t * H4 + row];
    }
    __syncthreads();
    if (tid < 4) {
      int j2 = bb * 4 + tid;
      float z0 = zl[tid * 4 + 0], z1 = zl[tid * 4 + 1], z2 = zl[tid * 4 + 2], z3 = zl[tid * 4 + 3];
      float cp = (t > 0) ? c1a[t * HSZ + j2] : 0.f;
      float c = sigf(z1) * cp + sigf(z0) * tanhf(z2);
      c1a[(t + 1) * HSZ + j2] = c;
      h1a[(t + 1) * HSZ + j2] = sigf(z3) * tanhf(c);
    }
  } else {
    rowX[tid] = h1a[(t + 1) * HSZ + tid];
    rowH[tid] = (t > 0) ? h2a[t * HSZ + tid] : 0.f;
    __syncthreads();
    float4 x0 = ((const float4*)rowX)[lane], x1 = ((const float4*)rowX)[lane + 64];
    float4 h0 = ((const float4*)rowH)[lane], h1v = ((const float4*)rowH)[lane + 64];
#pragma unroll
    for (int gg = 0; gg < 2; ++gg) {
      int g = g0 + gg;
      int row = j + (g << 9);
      const float4* wi = (const float4*)(Wih2 + (size_t)row * HSZ);
      const float4* wh = (const float4*)(Whh2 + (size_t)row * HSZ);
      float zs = wsum(dot4(wi[lane], x0) + dot4(wi[lane + 64], x1) +
                      dot4(wh[lane], h0) + dot4(wh[lane + 64], h1v));
      if (lane == 0) zl[lr * 4 + g] = zs + b2[row];
    }
    __syncthreads();
    if (tid < 4) {
      int j2 = bb * 4 + tid;
      float z0 = zl[tid * 4 + 0], z1 = zl[tid * 4 + 1], z2 = zl[tid * 4 + 2], z3 = zl[tid * 4 + 3];
      float cp = (t > 0) ? c2a[t * HSZ + j2] : 0.f;
      float c = sigf(z1) * cp + sigf(z0) * tanhf(z2);
      c2a[(t + 1) * HSZ + j2] = c;
      h2a[(t + 1) * HSZ + j2] = sigf(z3) * tanhf(c);
    }
  }
}

// ---------------- decoder ----------------

// Layer-1 cell with FUSED beam merge of the previous step's logits partials.
// MODE 0: step 0 (dinit — stage from encoder final state, bos embedding)
// MODE 1: step 1 (merge step-0 partials, BIN=1, init scores/bt)
// MODE 2: steps >=2 (full 9-candidate merge, BIN=3, bt update at col ti+1)
// Every block computes the merge redundantly (deterministic); block 0 persists
// scores/tokens/bt and the permuted layer-2 state hd2p/cd2p for k_dcell2.
template <int B, int BIN, int MODE>
__global__ void __launch_bounds__(512) k_dcell1(
    const float* __restrict__ Wih, const float* __restrict__ Whh,
    const float* __restrict__ bias,
    const float* __restrict__ emb_dec, const int* __restrict__ bosp,
    const float* __restrict__ h1prev, const float* __restrict__ c1prev,
    const float* __restrict__ h2prev, const float* __restrict__ c2prev,
    const float* __restrict__ pm, const float* __restrict__ ps,
    const float* __restrict__ pv, const int* __restrict__ pi,
    float* __restrict__ hout, float* __restrict__ cout,
    float* __restrict__ hd2p, float* __restrict__ cd2p,
    const float* __restrict__ scores_rd, float* __restrict__ scores_wr,
    const int* __restrict__ tokens_rd, int* __restrict__ tokens_wr,
    int* __restrict__ bt, int ti) {
  __shared__ float xl[B * HSZ], hl[B * HSZ], cl[B * HSZ], zl[8 * B];
  __shared__ float sM[3], sS[3], sV[3][3], sScore[3];
  __shared__ int sI[3][3], sOrig[3], sTokNew[3], sTokOld[3];
  int tid = threadIdx.x, wave = tid >> 6, lane = tid & 63;

  if (MODE >= 1) {
    if (wave < BIN) {
      int b = wave;
      float lm4[4], ls4[4];
      float M = -INFINITY;
#pragma unroll
      for (int q = 0; q < 4; ++q) {
        int blk2 = lane + q * 64;
        lm4[q] = pm[blk2 * 3 + b]; ls4[q] = ps[blk2 * 3 + b];
        M = fmaxf(M, lm4[q]);
      }
#pragma unroll
      for (int off = 32; off; off >>= 1) M = fmaxf(M, __shfl_xor(M, off, 64));
      float S = 0.f;
#pragma unroll
      for (int q = 0; q < 4; ++q) S += ls4[q] * expf(lm4[q] - M);
      S = wsum(S);
      float bv[3] = {-INFINITY, -INFINITY, -INFINITY};
      int bi3[3]  = {0x7fffffff, 0x7fffffff, 0x7fffffff};
#pragma unroll
      for (int q = 0; q < 4; ++q) {
        int blk2 = lane + q * 64;
#pragma unroll
        for (int k = 0; k < 3; ++k)
          ins3(bv, bi3, pv[(blk2 * 3 + b) * 3 + k], pi[(blk2 * 3 + b) * 3 + k]);
      }
#pragma unroll
      for (int off = 32; off; off >>= 1) {
        float ov[3]; int oi[3];
#pragma unroll
        for (int k = 0; k < 3; ++k) { ov[k] = __shfl_xor(bv[k], off, 64); oi[k] = __shfl_xor(bi3[k], off, 64); }
#pragma unroll
        for (int k = 0; k < 3; ++k) ins3(bv, bi3, ov[k], oi[k]);
      }
      if (lane == 0) {
        sM[b] = M; sS[b] = S;
#pragma unroll
        for (int k = 0; k < 3; ++k) { sV[b][k] = bv[k]; sI[b][k] = bi3[k]; }
      }
    }
    __syncthreads();
    if (tid == 0) {
      if (MODE == 1) {
        float off0 = -sM[0] - logf(sS[0]);
        for (int k = 0; k < 3; ++k) {
          sScore[k] = sV[0][k] + off0;
          sTokNew[k] = sI[0][k]; sOrig[k] = 0; sTokOld[k] = 0;
        }
      } else {
        float osc[3];
        for (int b = 0; b < 3; ++b) { osc[b] = scores_rd[b]; sTokOld[b] = tokens_rd[b]; }
        float cum[9];
        for (int b = 0; b < 3; ++b) {
          float o = osc[b] - sM[b] - logf(sS[b]);
          for (int k = 0; k < 3; ++k) cum[b * 3 + k] = sV[b][k] + o;
        }
        bool used[9] = {false, false, false, false, false, false, false, false, false};
        for (int k = 0; k < 3; ++k) {
          int bf = 0; float bb = -INFINITY;
          for (int f = 0; f < 9; ++f)
            if (!used[f] && cum[f] > bb) { bb = cum[f]; bf = f; }  // strict >: lowest flat idx on tie
          used[bf] = true;
          sScore[k] = bb;
          int ob = bf / 3;
          sOrig[k] = ob;
          sTokNew[k] = sI[ob][bf - ob * 3];
        }
      }
    }
    __syncthreads();
  }

  // stage x/h/c (gather through merge results); block 0 also persists small state
  if (MODE == 0) {
    int bos = bosp[0];
    for (int i = tid; i < B * HSZ; i += 512) {
      xl[i] = emb_dec[(size_t)bos * HSZ + i];
      hl[i] = h1prev[i]; cl[i] = c1prev[i];
    }
    if (blockIdx.x == 0) {
      for (int i = tid; i < B * HSZ; i += 512) { hd2p[i] = h2prev[i]; cd2p[i] = c2prev[i]; }
    }
  } else {
    for (int i = tid; i < B * HSZ; i += 512) {
      int b = i >> 9, e = i & 511;
      xl[i] = emb_dec[(size_t)sTokNew[b] * HSZ + e];
      hl[i] = h1prev[sOrig[b] * HSZ + e];
      cl[i] = c1prev[sOrig[b] * HSZ + e];
    }
    if (blockIdx.x == 0) {
      for (int i = tid; i < B * HSZ; i += 512) {
        int b = i >> 9, e = i & 511;
        hd2p[i] = h2prev[sOrig[b] * HSZ + e];
        cd2p[i] = c2prev[sOrig[b] * HSZ + e];
      }
      if (MODE == 1) {
        int bos = bosp[0];
        for (int idx = tid; idx < BEAM * TMAX; idx += 512) bt[idx] = bos;  // buffer 0
      } else {
        const int* src = bt + (ti & 1) * (BEAM * TMAX);
        int* dst = bt + ((ti + 1) & 1) * (BEAM * TMAX);
        for (int idx = tid; idx < BEAM * TMAX; idx += 512) {
          int k = idx / TMAX, jj = idx % TMAX, o = sOrig[k];
          dst[idx] = (jj == ti + 1) ? sTokOld[o] : src[o * TMAX + jj];
        }
      }
      if (tid < 3) { scores_wr[tid] = sScore[tid]; tokens_wr[tid] = sTokNew[tid]; }
    }
  }
  __syncthreads();

  // LSTM layer-1 cell: one (row,gate) per wave across 256 blocks x 8 waves
  int lr = wave >> 2;
  int g  = wave & 3;
  int j  = blockIdx.x * 2 + lr;
  int row = j + (g << 9);
  const float4* wi = (const float4*)(Wih + (size_t)row * HSZ);
  const float4* wh = (const float4*)(Whh + (size_t)row * HSZ);
  float4 wi0 = wi[lane], wi1 = wi[lane + 64], wh0 = wh[lane], wh1 = wh[lane + 64];
  float bb = bias[row];
#pragma unroll
  for (int b = 0; b < B; ++b) {
    float4 xv0 = ((const float4*)(xl + b * HSZ))[lane];
    float4 xv1 = ((const float4*)(xl + b * HSZ))[lane + 64];
    float4 hv0 = ((const float4*)(hl + b * HSZ))[lane];
    float4 hv1 = ((const float4*)(hl + b * HSZ))[lane + 64];
    float acc = dot4(wi0, xv0) + dot4(wi1, xv1) + dot4(wh0, hv0) + dot4(wh1, hv1);
    float z = wsum(acc) + bb;
    if (lane == 0) zl[(lr * 4 + g) * B + b] = z;
  }
  __syncthreads();
  for (int q = tid; q < 2 * B; q += 512) {
    int lr2 = q / B, b = q % B;
    int j2 = blockIdx.x * 2 + lr2;
    float z0 = zl[(lr2 * 4 + 0) * B + b], z1 = zl[(lr2 * 4 + 1) * B + b];
    float z2 = zl[(lr2 * 4 + 2) * B + b], z3 = zl[(lr2 * 4 + 3) * B + b];
    float c = sigf(z1) * cl[b * HSZ + j2] + sigf(z0) * tanhf(z2);
    cout[b * HSZ + j2] = c;
    hout[b * HSZ + j2] = sigf(z3) * tanhf(c);
  }
}

// layer-2 cell (plain; x = layer-1 output, h/c = permuted layer-2 state)
template <int B>
__global__ void __launch_bounds__(512) k_dcell2(const float* __restrict__ Wih,
                                                const float* __restrict__ Whh,
                                                const float* __restrict__ bias,
                                                const float* __restrict__ x,
                                                const float* __restrict__ hin,
                                                const float* __restrict__ cin,
                                                float* __restrict__ hout, float* __restrict__ cout) {
  __shared__ float xl[B * HSZ], hl[B * HSZ], cl[B * HSZ], zl[8 * B];
  int tid = threadIdx.x;
  for (int i = tid; i < B * HSZ; i += 512) { xl[i] = x[i]; hl[i] = hin[i]; cl[i] = cin[i]; }
  __syncthreads();
  int wave = tid >> 6, lane = tid & 63;
  int lr = wave >> 2;
  int g  = wave & 3;
  int j  = blockIdx.x * 2 + lr;
  int row = j + (g << 9);
  const float4* wi = (const float4*)(Wih + (size_t)row * HSZ);
  const float4* wh = (const float4*)(Whh + (size_t)row * HSZ);
  float4 wi0 = wi[lane], wi1 = wi[lane + 64], wh0 = wh[lane], wh1 = wh[lane + 64];
  float bb = bias[row];
#pragma unroll
  for (int b = 0; b < B; ++b) {
    float4 xv0 = ((const float4*)(xl + b * HSZ))[lane];
    float4 xv1 = ((const float4*)(xl + b * HSZ))[lane + 64];
    float4 hv0 = ((const float4*)(hl + b * HSZ))[lane];
    float4 hv1 = ((const float4*)(hl + b * HSZ))[lane + 64];
    float acc = dot4(wi0, xv0) + dot4(wi1, xv1) + dot4(wh0, hv0) + dot4(wh1, hv1);
    float z = wsum(acc) + bb;
    if (lane == 0) zl[(lr * 4 + g) * B + b] = z;
  }
  __syncthreads();
  for (int q = tid; q < 2 * B; q += 512) {
    int lr2 = q / B, b = q % B;
    int j2 = blockIdx.x * 2 + lr2;
    float z0 = zl[(lr2 * 4 + 0) * B + b], z1 = zl[(lr2 * 4 + 1) * B + b];
    float z2 = zl[(lr2 * 4 + 2) * B + b], z3 = zl[(lr2 * 4 + 3) * B + b];
    float c = sigf(z1) * cl[b * HSZ + j2] + sigf(z0) * tanhf(z2);
    cout[b * HSZ + j2] = c;
    hout[b * HSZ + j2] = sigf(z3) * tanhf(c);
  }
}

// attention + context + feat; 64 blocks x 512
template <int B>
__global__ void __launch_bounds__(512) k_attfeat(const float* __restrict__ h2,
                                                 const float* __restrict__ enc,
                                                 const float* __restrict__ Wc,
                                                 float* __restrict__ feat) {
  __shared__ float xs[BEAM * HSZ], at[BEAM * SEQ], xcs[BEAM * 1024];
  int tid = threadIdx.x;
  for (int i = tid; i < B * HSZ; i += 512) xs[i] = h2[i];
  __syncthreads();
  if (tid < B * SEQ) {
    int b = tid >> 6, s2 = tid & 63;
    const float* er = enc + (s2 + 1) * HSZ;
    const float* xb = xs + b * HSZ;
    float acc = 0.f;
    for (int e = 0; e < HSZ; e += 4) {
      float4 ev = *(const float4*)(er + e);
      acc += ev.x * xb[e] + ev.y * xb[e + 1] + ev.z * xb[e + 2] + ev.w * xb[e + 3];
    }
    at[tid] = acc;
  }
  __syncthreads();
  if (tid < B) {
    float m = -INFINITY;
    for (int s2 = 0; s2 < SEQ; ++s2) m = fmaxf(m, at[tid * SEQ + s2]);
    float s = 0.f;
    for (int s2 = 0; s2 < SEQ; ++s2) { float e = expf(at[tid * SEQ + s2] - m); at[tid * SEQ + s2] = e; s += e; }
    float inv = 1.f / s;
    for (int s2 = 0; s2 < SEQ; ++s2) at[tid * SEQ + s2] *= inv;
  }
  __syncthreads();
  if (tid < 128) {
    int h4 = tid * 4;
    float4 acc[B];
#pragma unroll
    for (int b = 0; b < B; ++b) acc[b] = make_float4(0.f, 0.f, 0.f, 0.f);
    for (int s2 = 0; s2 < SEQ; ++s2) {
      float4 ev = *(const float4*)(enc + (s2 + 1) * HSZ + h4);
#pragma unroll
      for (int b = 0; b < B; ++b) {
        float a = at[b * SEQ + s2];
        acc[b].x += a * ev.x; acc[b].y += a * ev.y; acc[b].z += a * ev.z; acc[b].w += a * ev.w;
      }
    }
#pragma unroll
    for (int b = 0; b < B; ++b) *(float4*)(xcs + b * 1024 + 512 + h4) = acc[b];
  }
  for (int i = tid; i < B * HSZ; i += 512) {
    int b = i >> 9, hcol = i & 511;
    xcs[b * 1024 + hcol] = xs[b * HSZ + hcol];
  }
  __syncthreads();
  int wave = tid >> 6, lane = tid & 63;
  int j = blockIdx.x * 8 + wave;
  const float4* w = (const float4*)(Wc + (size_t)j * 1024);
  float4 w0 = w[lane], w1 = w[lane + 64], w2 = w[lane + 128], w3 = w[lane + 192];
#pragma unroll
  for (int b = 0; b < B; ++b) {
    const float4* xb = (const float4*)(xcs + b * 1024);
    float acc = dot4(w0, xb[lane]) + dot4(w1, xb[lane + 64]) +
                dot4(w2, xb[lane + 128]) + dot4(w3, xb[lane + 192]);
    acc = wsum(acc);
    if (lane == 0) feat[b * HSZ + j] = tanhf(acc);
  }
}

// logits + streaming (max, sumexp, top3); 256 blocks x 8 waves, 16 rows/wave, 8-batched loads
template <int B>
__global__ void __launch_bounds__(512) k_logits(const float* __restrict__ Wout,
                                                const float* __restrict__ bout,
                                                const float* __restrict__ feat,
                                                float* __restrict__ pm, float* __restrict__ ps,
                                                float* __restrict__ pv, int* __restrict__ pi) {
  __shared__ float fst[BEAM * HSZ];
  int tid = threadIdx.x;
  for (int i = tid; i < B * HSZ; i += 512) fst[i] = feat[i];
  __syncthreads();
  int wave = tid >> 6, lane = tid & 63;
  int gid  = blockIdx.x * 8 + wave;
  float4 f0[B], f1[B];
#pragma unroll
  for (int b = 0; b < B; ++b) {
    f0[b] = ((const float4*)(fst + b * HSZ))[lane];
    f1[b] = ((const float4*)(fst + b * HSZ))[lane + 64];
  }
  float m[B], ss[B], tv[B][3];
  int tix[B][3];
#pragma unroll
  for (int b = 0; b < B; ++b) {
    m[b] = -INFINITY; ss[b] = 0.f;
#pragma unroll
    for (int k = 0; k < 3; ++k) { tv[b][k] = -INFINITY; tix[b][k] = 0x7fffffff; }
  }
  for (int k0 = 0; k0 < 16; k0 += 8) {
    float4 a0[8], a1[8]; float ab[8]; int vr[8];
#pragma unroll
    for (int u = 0; u < 8; ++u) {
      int v = gid + (k0 + u) * 2048;
      vr[u] = v;
      if (v < VOC) {
        const float4* wr = (const float4*)(Wout + (size_t)v * HSZ);
        a0[u] = wr[lane]; a1[u] = wr[lane + 64]; ab[u] = bout[v];
      } else {
        a0[u] = make_float4(0.f, 0.f, 0.f, 0.f); a1[u] = a0[u]; ab[u] = 0.f;
      }
    }
#pragma unroll
    for (int u = 0; u < 8; ++u) {
      if (vr[u] >= VOC) continue;  // wave-uniform
#pragma unroll
      for (int b = 0; b < B; ++b) {
        float acc = wsum(dot4(a0[u], f0[b]) + dot4(a1[u], f1[b])) + ab[u];
        float mo = m[b], mn = fmaxf(mo, acc);
        ss[b] = ss[b] * expf(mo - mn) + expf(acc - mn);
        m[b]  = mn;
        ins3(tv[b], tix[b], acc, vr[u]);
      }
    }
  }
  __shared__ float lm[8][3], lss[8][3], lv[8][3][3];
  __shared__ int li[8][3][3];
  if (lane == 0) {
#pragma unroll
    for (int b = 0; b < B; ++b) {
      lm[wave][b] = m[b]; lss[wave][b] = ss[b];
#pragma unroll
      for (int k = 0; k < 3; ++k) { lv[wave][b][k] = tv[b][k]; li[wave][b][k] = tix[b][k]; }
    }
  }
  __syncthreads();
  if (tid < B) {
    int b = tid;
    float M = -INFINITY;
#pragma unroll
    for (int w2 = 0; w2 < 8; ++w2) M = fmaxf(M, lm[w2][b]);
    float S = 0.f;
#pragma unroll
    for (int w2 = 0; w2 < 8; ++w2) S += lss[w2][b] * expf(lm[w2][b] - M);
    float bv[3] = {-INFINITY, -INFINITY, -INFINITY};
    int bi3[3]  = {0x7fffffff, 0x7fffffff, 0x7fffffff};
#pragma unroll
    for (int w2 = 0; w2 < 8; ++w2)
#pragma unroll
      for (int k = 0; k < 3; ++k) ins3(bv, bi3, lv[w2][b][k], li[w2][b][k]);
    int o = blockIdx.x * 3 + b;
    pm[o] = M; ps[o] = S;
#pragma unroll
    for (int k = 0; k < 3; ++k) { pv[o * 3 + k] = bv[k]; pi[o * 3 + k] = bi3[k]; }
  }
}

// tail: final merge (step 49, ti=48) + output write; 1 block x 256
__global__ void __launch_bounds__(256) k_tail(const float* __restrict__ pm,
                                              const float* __restrict__ ps,
                                              const float* __restrict__ pv,
                                              const int* __restrict__ pi,
                                              const float* __restrict__ scores_rd,
                                              const int* __restrict__ tokens_rd,
                                              int* __restrict__ bt, int* __restrict__ outp) {
  const int ti = TMAX - 2;
  __shared__ float sM[3], sS[3], sV[3][3], sScore[3];
  __shared__ int sI[3][3], sOrig[3], sTokOld[3], sKstar;
  int tid = threadIdx.x, wave = tid >> 6, lane = tid & 63;
  if (wave < 3) {
    int b = wave;
    float lm4[4], ls4[4];
    float M = -INFINITY;
#pragma unroll
    for (int q = 0; q < 4; ++q) {
      int blk2 = lane + q * 64;
      lm4[q] = pm[blk2 * 3 + b]; ls4[q] = ps[blk2 * 3 + b];
      M = fmaxf(M, lm4[q]);
    }
#pragma unroll
    for (int off = 32; off; off >>= 1) M = fmaxf(M, __shfl_xor(M, off, 64));
    float S = 0.f;
#pragma unroll
    for (int q = 0; q < 4; ++q) S += ls4[q] * expf(lm4[q] - M);
    S = wsum(S);
    float bv[3] = {-INFINITY, -INFINITY, -INFINITY};
    int bi3[3]  = {0x7fffffff, 0x7fffffff, 0x7fffffff};
#pragma unroll
    for (int q = 0; q < 4; ++q) {
      int blk2 = lane + q * 64;
#pragma unroll
      for (int k = 0; k < 3; ++k)
        ins3(bv, bi3, pv[(blk2 * 3 + b) * 3 + k], pi[(blk2 * 3 + b) * 3 + k]);
    }
#pragma unroll
    for (int off = 32; off; off >>= 1) {
      float ov[3]; int oi[3];
#pragma unroll
      for (int k = 0; k < 3; ++k) { ov[k] = __shfl_xor(bv[k], off, 64); oi[k] = __shfl_xor(bi3[k], off, 64); }
#pragma unroll
      for (int k = 0; k < 3; ++k) ins3(bv, bi3, ov[k], oi[k]);
    }
    if (lane == 0) {
      sM[b] = M; sS[b] = S;
#pragma unroll
      for (int k = 0; k < 3; ++k) { sV[b][k] = bv[k]; sI[b][k] = bi3[k]; }
    }
  }
  __syncthreads();
  if (tid == 0) {
    float osc[3];
    for (int b = 0; b < 3; ++b) { osc[b] = scores_rd[b]; sTokOld[b] = tokens_rd[b]; }
    float cum[9];
    for (int b = 0; b < 3; ++b) {
      float o = osc[b] - sM[b] - logf(sS[b]);
      for (int k = 0; k < 3; ++k) cum[b * 3 + k] = sV[b][k] + o;
    }
    bool used[9] = {false, false, false, false, false, false, false, false, false};
    for (int k = 0; k < 3; ++k) {
      int bf = 0; float bb = -INFINITY;
      for (int f = 0; f < 9; ++f)
        if (!used[f] && cum[f] > bb) { bb = cum[f]; bf = f; }
      used[bf] = true;
      sScore[k] = bb;
      sOrig[k] = bf / 3;
    }
    float bb = -INFINITY; int kk = 0;
    for (int k = 0; k < 3; ++k) if (sScore[k] > bb) { bb = sScore[k]; kk = k; }
    sKstar = kk;
  }
  __syncthreads();
  const int* src = bt + (ti & 1) * (BEAM * TMAX);
  int* dst = bt + ((ti + 1) & 1) * (BEAM * TMAX);
  for (int idx = tid; idx < BEAM * TMAX; idx += 256) {
    int k = idx / TMAX, jj = idx % TMAX, o = sOrig[k];
    dst[idx] = (jj == ti + 1) ? sTokOld[o] : src[o * TMAX + jj];
  }
  __syncthreads();
  for (int jj = tid; jj < TMAX; jj += 256) outp[jj] = dst[sKstar * TMAX + jj];
}

extern "C" void kernel_launch(void* const* d_in, const int* in_sizes, int n_in,
                              void* d_out, int out_size, void* d_ws, size_t ws_size,
                              hipStream_t stream) {
  const int*   seq     = (const int*)d_in[0];
  const float* emb_enc = (const float*)d_in[1];
  const float* Wih_enc = (const float*)d_in[2];
  const float* Whh_enc = (const float*)d_in[3];
  const float* b_enc   = (const float*)d_in[4];
  const float* emb_dec = (const float*)d_in[5];
  const float* Wih_dec = (const float*)d_in[6];
  const float* Whh_dec = (const float*)d_in[7];
  const float* b_dec   = (const float*)d_in[8];
  const float* W_c     = (const float*)d_in[9];
  const float* W_out   = (const float*)d_in[10];
  const float* b_out   = (const float*)d_in[11];
  const int*   bosp    = (const int*)d_in[14];

  float* w = (float*)d_ws;
  float* xp1     = w; w += SEQ * H4;
  float* h1a     = w; w += (SEQ + 1) * HSZ;
  float* c1a     = w; w += (SEQ + 1) * HSZ;
  float* h2a     = w; w += (SEQ + 1) * HSZ;
  float* c2a     = w; w += (SEQ + 1) * HSZ;
  float* hdn1    = w; w += 2 * BEAM * HSZ;   // [2 parities][3*512] layer-1 h
  float* cdn1    = w; w += 2 * BEAM * HSZ;
  float* hdn2    = w; w += 2 * BEAM * HSZ;   // layer-2 h
  float* cdn2    = w; w += 2 * BEAM * HSZ;
  float* hd2p    = w; w += BEAM * HSZ;       // permuted layer-2 state for dcell2
  float* cd2p    = w; w += BEAM * HSZ;
  float* feat    = w; w += BEAM * HSZ;
  float* pm      = w; w += 256 * 3;
  float* ps      = w; w += 256 * 3;
  float* pv      = w; w += 256 * 3 * 3;
  float* sb      = w; w += 2 * 4;            // scores double-buffer
  int* pi     = (int*)w; w += 256 * 3 * 3;
  int* tb     = (int*)w; w += 2 * 4;         // tokens double-buffer
  int* bt     = (int*)w; w += 2 * BEAM * TMAX + 4;
  int* outp   = (int*)d_out;

  k_xw1<<<256, 512, 0, stream>>>(Wih_enc, b_enc, emb_enc, seq, xp1);
  for (int s = 0; s <= SEQ; ++s)
    k_encslot<<<256, 512, 0, stream>>>(Whh_enc, Wih_enc + LOFF, Whh_enc + LOFF, b_enc + H4,
                                       xp1, h1a, c1a, h2a, c2a, s);

  for (int s = 0; s < TMAX; ++s) {
    int rp = (s - 1) & 1, wp = s & 1;
    if (s == 0) {
      k_dcell1<1, 1, 0><<<256, 512, 0, stream>>>(
          Wih_dec, Whh_dec, b_dec, emb_dec, bosp,
          h1a + SEQ * HSZ, c1a + SEQ * HSZ, h2a + SEQ * HSZ, c2a + SEQ * HSZ,
          pm, ps, pv, pi,
          hdn1 + 0, cdn1 + 0, hd2p, cd2p,
          sb, sb, tb, tb, bt, 0);
      k_dcell2<1><<<256, 512, 0, stream>>>(Wih_dec + LOFF, Whh_dec + LOFF, b_dec + H4,
                                           hdn1 + 0, hd2p, cd2p, hdn2 + 0, cdn2 + 0);
      k_attfeat<1><<<64, 512, 0, stream>>>(hdn2 + 0, h2a, W_c, feat);
      k_logits<1><<<256, 512, 0, stream>>>(W_out, b_out, feat, pm, ps, pv, pi);
    } else {
      float* h1p = hdn1 + rp * BEAM * HSZ; float* c1p = cdn1 + rp * BEAM * HSZ;
      float* h2p = hdn2 + rp * BEAM * HSZ; float* c2p = cdn2 + rp * BEAM * HSZ;
      float* h1o = hdn1 + wp * BEAM * HSZ; float* c1o = cdn1 + wp * BEAM * HSZ;
      float* h2o = hdn2 + wp * BEAM * HSZ; float* c2o = cdn2 + wp * BEAM * HSZ;
      if (s == 1)
        k_dcell1<3, 1, 1><<<256, 512, 0, stream>>>(
            Wih_dec, Whh_dec, b_dec, emb_dec, bosp,
            h1p, c1p, h2p, c2p, pm, ps, pv, pi,
            h1o, c1o, hd2p, cd2p,
            sb + rp * 4, sb + wp * 4, tb + rp * 4, tb + wp * 4, bt, -1);
      else
        k_dcell1<3, 3, 2><<<256, 512, 0, stream>>>(
            Wih_dec, Whh_dec, b_dec, emb_dec, bosp,
            h1p, c1p, h2p, c2p, pm, ps, pv, pi,
            h1o, c1o, hd2p, cd2p,
            sb + rp * 4, sb + wp * 4, tb + rp * 4, tb + wp * 4, bt, s - 2);
      k_dcell2<3><<<256, 512, 0, stream>>>(Wih_dec + LOFF, Whh_dec + LOFF, b_dec + H4,
                                           h1o, hd2p, cd2p, h2o, c2o);
      k_attfeat<3><<<64, 512, 0, stream>>>(h2o, h2a, W_c, feat);
      k_logits<3><<<256, 512, 0, stream>>>(W_out, b_out, feat, pm, ps, pv, pi);
    }
  }
  // final merge of step-49 partials + output (scores/tokens written by step 49: parity 1)
  k_tail<<<1, 256, 0, stream>>>(pm, ps, pv, pi, sb + 4, tb + 4, bt, outp);
}

// Round 11
// 3550.332 us; speedup vs baseline: 1.2820x; 1.0125x over previous
//
#include <hip/hip_runtime.h>
#include <math.h>

// Problem constants (fixed by the reference module)
#define HSZ   512
#define H4    2048
#define SEQ   64
#define VOC   32000
#define BEAM  3
#define TMAX  50
#define FLS   16   // flag line stride in ints (64 B)

#define LOFF  ((size_t)H4 * HSZ)   // per-layer weight stride

__device__ __forceinline__ float wsum(float v) {
#pragma unroll
  for (int off = 32; off; off >>= 1) v += __shfl_xor(v, off, 64);
  return v;
}
__device__ __forceinline__ float dot4(float4 a, float4 b) {
  return a.x * b.x + a.y * b.y + a.z * b.z + a.w * b.w;
}
__device__ __forceinline__ float sigf(float x) { return 1.f / (1.f + expf(-x)); }

__device__ __forceinline__ bool better(float v1, int i1, float v2, int i2) {
  return (v1 > v2) || (v1 == v2 && i1 < i2);  // jax.lax.top_k order: value desc, index asc
}
__device__ __forceinline__ void ins3(float* v, int* idx, float nv, int ni) {
  if (better(nv, ni, v[2], idx[2])) {
    if (better(nv, ni, v[1], idx[1])) {
      v[2] = v[1]; idx[2] = idx[1];
      if (better(nv, ni, v[0], idx[0])) { v[1] = v[0]; idx[1] = idx[0]; v[0] = nv; idx[0] = ni; }
      else { v[1] = nv; idx[1] = ni; }
    } else { v[2] = nv; idx[2] = ni; }
  }
}

// coherent accessors (agent scope, relaxed) — validated bit-exact in rounds 5-8
__device__ __forceinline__ float agld(const float* p) {
  return __hip_atomic_load(p, __ATOMIC_RELAXED, __HIP_MEMORY_SCOPE_AGENT);
}
__device__ __forceinline__ void agst(float* p, float v) {
  __hip_atomic_store(p, v, __ATOMIC_RELAXED, __HIP_MEMORY_SCOPE_AGENT);
}
__device__ __forceinline__ int agldi(const int* p) {
  return __hip_atomic_load(p, __ATOMIC_RELAXED, __HIP_MEMORY_SCOPE_AGENT);
}
__device__ __forceinline__ void agsti(int* p, int v) {
  __hip_atomic_store(p, v, __ATOMIC_RELAXED, __HIP_MEMORY_SCOPE_AGENT);
}

// ---------------- encoder ----------------

__global__ void __launch_bounds__(512) k_xw1(const float* __restrict__ Wih,
                                             const float* __restrict__ bias,
                                             const float* __restrict__ emb,
                                             const int* __restrict__ seq,
                                             float* __restrict__ xp1) {
  int t    = threadIdx.x & 63;
  int wave = threadIdx.x >> 6;
  int r    = blockIdx.x * 8 + wave;
  int tok  = seq[t];
  const float* xr = emb + (size_t)tok * HSZ;
  const float* wr = Wih + (size_t)r * HSZ;
  float acc = 0.f;
  for (int e = 0; e < HSZ; e += 4) {
    float4 wv = *(const float4*)(wr + e);
    float4 xv = *(const float4*)(xr + e);
    acc += dot4(wv, xv);
  }
  xp1[t * H4 + r] = acc + bias[r];
}

__global__ void __launch_bounds__(512) k_encslot(const float* __restrict__ Whh1,
                                                 const float* __restrict__ Wih2,
                                                 const float* __restrict__ Whh2,
                                                 const float* __restrict__ b2,
                                                 const float* __restrict__ xp1,
                                                 float* __restrict__ h1a, float* __restrict__ c1a,
                                                 float* __restrict__ h2a, float* __restrict__ c2a,
                                                 int s) {
  __shared__ float rowX[HSZ], rowH[HSZ], zl[16];
  int tid = threadIdx.x, wave = tid >> 6, lane = tid & 63;
  bool l2 = blockIdx.x >= 128;
  int t = l2 ? s - 1 : s;
  if (t < 0 || t >= SEQ) return;
  int bb = blockIdx.x & 127;
  int lr = wave >> 1;
  int j  = bb * 4 + lr;
  int g0 = (wave & 1) * 2;
  if (!l2) {
    rowX[tid] = (t > 0) ? h1a[t * HSZ + tid] : 0.f;
    __syncthreads();
    float4 h0 = ((const float4*)rowX)[lane], h1v = ((const float4*)rowX)[lane + 64];
#pragma unroll
    for (int gg = 0; gg < 2; ++gg) {
      int g = g0 + gg;
      int row = j + (g << 9);
      const float4* wr = (const float4*)(Whh1 + (size_t)row * HSZ);
      float zs = wsum(dot4(wr[lane], h0) + dot4(wr[lane + 64], h1v));
      if (lane == 0) zl[lr * 4 + g] = zs + xp1[t * H4 + row];
    }
    __syncthreads();
    if (tid < 4) {
      int j2 = bb * 4 + tid;
      float z0 = zl[tid * 4 + 0], z1 = zl[tid * 4 + 1], z2 = zl[tid * 4 + 2], z3 = zl[tid * 4 + 3];
      float cp = (t > 0) ? c1a[t * HSZ + j2] : 0.f;
      float c = sigf(z1) * cp + sigf(z0) * tanhf(z2);
      c1a[(t + 1) * HSZ + j2] = c;
      h1a[(t + 1) * HSZ + j2] = sigf(z3) * tanhf(c);
    }
  } else {
    rowX[tid] = h1a[(t + 1) * HSZ + tid];
    rowH[tid] = (t > 0) ? h2a[t * HSZ + tid] : 0.f;
    __syncthreads();
    float4 x0 = ((const float4*)rowX)[lane], x1 = ((const float4*)rowX)[lane + 64];
    float4 h0 = ((const float4*)rowH)[lane], h1v = ((const float4*)rowH)[lane + 64];
#pragma unroll
    for (int gg = 0; gg < 2; ++gg) {
      int g = g0 + gg;
      int row = j + (g << 9);
      const float4* wi = (const float4*)(Wih2 + (size_t)row * HSZ);
      const float4* wh = (const float4*)(Whh2 + (size_t)row * HSZ);
      float zs = wsum(dot4(wi[lane], x0) + dot4(wi[lane + 64], x1) +
                      dot4(wh[lane], h0) + dot4(wh[lane + 64], h1v));
      if (lane == 0) zl[lr * 4 + g] = zs + b2[row];
    }
    __syncthreads();
    if (tid < 4) {
      int j2 = bb * 4 + tid;
      float z0 = zl[tid * 4 + 0], z1 = zl[tid * 4 + 1], z2 = zl[tid * 4 + 2], z3 = zl[tid * 4 + 3];
      float cp = (t > 0) ? c2a[t * HSZ + j2] : 0.f;
      float c = sigf(z1) * cp + sigf(z0) * tanhf(z2);
      c2a[(t + 1) * HSZ + j2] = c;
      h2a[(t + 1) * HSZ + j2] = sigf(z3) * tanhf(c);
    }
  }
}

// ---------------- decoder ----------------

// Layer-1 cell with FUSED beam merge (round-10, passed bit-exact).
template <int B, int BIN, int MODE>
__global__ void __launch_bounds__(512) k_dcell1(
    const float* __restrict__ Wih, const float* __restrict__ Whh,
    const float* __restrict__ bias,
    const float* __restrict__ emb_dec, const int* __restrict__ bosp,
    const float* __restrict__ h1prev, const float* __restrict__ c1prev,
    const float* __restrict__ h2prev, const float* __restrict__ c2prev,
    const float* __restrict__ pm, const float* __restrict__ ps,
    const float* __restrict__ pv, const int* __restrict__ pi,
    float* __restrict__ hout, float* __restrict__ cout,
    float* __restrict__ hd2p, float* __restrict__ cd2p,
    const float* __restrict__ scores_rd, float* __restrict__ scores_wr,
    const int* __restrict__ tokens_rd, int* __restrict__ tokens_wr,
    int* __restrict__ bt, int ti) {
  __shared__ float xl[B * HSZ], hl[B * HSZ], cl[B * HSZ], zl[8 * B];
  __shared__ float sM[3], sS[3], sV[3][3], sScore[3];
  __shared__ int sI[3][3], sOrig[3], sTokNew[3], sTokOld[3];
  int tid = threadIdx.x, wave = tid >> 6, lane = tid & 63;

  if (MODE >= 1) {
    if (wave < BIN) {
      int b = wave;
      float lm4[4], ls4[4];
      float M = -INFINITY;
#pragma unroll
      for (int q = 0; q < 4; ++q) {
        int blk2 = lane + q * 64;
        lm4[q] = pm[blk2 * 3 + b]; ls4[q] = ps[blk2 * 3 + b];
        M = fmaxf(M, lm4[q]);
      }
#pragma unroll
      for (int off = 32; off; off >>= 1) M = fmaxf(M, __shfl_xor(M, off, 64));
      float S = 0.f;
#pragma unroll
      for (int q = 0; q < 4; ++q) S += ls4[q] * expf(lm4[q] - M);
      S = wsum(S);
      float bv[3] = {-INFINITY, -INFINITY, -INFINITY};
      int bi3[3]  = {0x7fffffff, 0x7fffffff, 0x7fffffff};
#pragma unroll
      for (int q = 0; q < 4; ++q) {
        int blk2 = lane + q * 64;
#pragma unroll
        for (int k = 0; k < 3; ++k)
          ins3(bv, bi3, pv[(blk2 * 3 + b) * 3 + k], pi[(blk2 * 3 + b) * 3 + k]);
      }
#pragma unroll
      for (int off = 32; off; off >>= 1) {
        float ov[3]; int oi[3];
#pragma unroll
        for (int k = 0; k < 3; ++k) { ov[k] = __shfl_xor(bv[k], off, 64); oi[k] = __shfl_xor(bi3[k], off, 64); }
#pragma unroll
        for (int k = 0; k < 3; ++k) ins3(bv, bi3, ov[k], oi[k]);
      }
      if (lane == 0) {
        sM[b] = M; sS[b] = S;
#pragma unroll
        for (int k = 0; k < 3; ++k) { sV[b][k] = bv[k]; sI[b][k] = bi3[k]; }
      }
    }
    __syncthreads();
    if (tid == 0) {
      if (MODE == 1) {
        float off0 = -sM[0] - logf(sS[0]);
        for (int k = 0; k < 3; ++k) {
          sScore[k] = sV[0][k] + off0;
          sTokNew[k] = sI[0][k]; sOrig[k] = 0; sTokOld[k] = 0;
        }
      } else {
        float osc[3];
        for (int b = 0; b < 3; ++b) { osc[b] = scores_rd[b]; sTokOld[b] = tokens_rd[b]; }
        float cum[9];
        for (int b = 0; b < 3; ++b) {
          float o = osc[b] - sM[b] - logf(sS[b]);
          for (int k = 0; k < 3; ++k) cum[b * 3 + k] = sV[b][k] + o;
        }
        bool used[9] = {false, false, false, false, false, false, false, false, false};
        for (int k = 0; k < 3; ++k) {
          int bf = 0; float bb = -INFINITY;
          for (int f = 0; f < 9; ++f)
            if (!used[f] && cum[f] > bb) { bb = cum[f]; bf = f; }  // strict >: lowest flat idx on tie
          used[bf] = true;
          sScore[k] = bb;
          int ob = bf / 3;
          sOrig[k] = ob;
          sTokNew[k] = sI[ob][bf - ob * 3];
        }
      }
    }
    __syncthreads();
  }

  if (MODE == 0) {
    int bos = bosp[0];
    for (int i = tid; i < B * HSZ; i += 512) {
      xl[i] = emb_dec[(size_t)bos * HSZ + i];
      hl[i] = h1prev[i]; cl[i] = c1prev[i];
    }
    if (blockIdx.x == 0) {
      for (int i = tid; i < B * HSZ; i += 512) { hd2p[i] = h2prev[i]; cd2p[i] = c2prev[i]; }
    }
  } else {
    for (int i = tid; i < B * HSZ; i += 512) {
      int b = i >> 9, e = i & 511;
      xl[i] = emb_dec[(size_t)sTokNew[b] * HSZ + e];
      hl[i] = h1prev[sOrig[b] * HSZ + e];
      cl[i] = c1prev[sOrig[b] * HSZ + e];
    }
    if (blockIdx.x == 0) {
      for (int i = tid; i < B * HSZ; i += 512) {
        int b = i >> 9, e = i & 511;
        hd2p[i] = h2prev[sOrig[b] * HSZ + e];
        cd2p[i] = c2prev[sOrig[b] * HSZ + e];
      }
      if (MODE == 1) {
        int bos = bosp[0];
        for (int idx = tid; idx < BEAM * TMAX; idx += 512) bt[idx] = bos;  // buffer 0
      } else {
        const int* src = bt + (ti & 1) * (BEAM * TMAX);
        int* dst = bt + ((ti + 1) & 1) * (BEAM * TMAX);
        for (int idx = tid; idx < BEAM * TMAX; idx += 512) {
          int k = idx / TMAX, jj = idx % TMAX, o = sOrig[k];
          dst[idx] = (jj == ti + 1) ? sTokOld[o] : src[o * TMAX + jj];
        }
      }
      if (tid < 3) { scores_wr[tid] = sScore[tid]; tokens_wr[tid] = sTokNew[tid]; }
    }
  }
  __syncthreads();

  int lr = wave >> 2;
  int g  = wave & 3;
  int j  = blockIdx.x * 2 + lr;
  int row = j + (g << 9);
  const float4* wi = (const float4*)(Wih + (size_t)row * HSZ);
  const float4* wh = (const float4*)(Whh + (size_t)row * HSZ);
  float4 wi0 = wi[lane], wi1 = wi[lane + 64], wh0 = wh[lane], wh1 = wh[lane + 64];
  float bb = bias[row];
#pragma unroll
  for (int b = 0; b < B; ++b) {
    float4 xv0 = ((const float4*)(xl + b * HSZ))[lane];
    float4 xv1 = ((const float4*)(xl + b * HSZ))[lane + 64];
    float4 hv0 = ((const float4*)(hl + b * HSZ))[lane];
    float4 hv1 = ((const float4*)(hl + b * HSZ))[lane + 64];
    float acc = dot4(wi0, xv0) + dot4(wi1, xv1) + dot4(wh0, hv0) + dot4(wh1, hv1);
    float z = wsum(acc) + bb;
    if (lane == 0) zl[(lr * 4 + g) * B + b] = z;
  }
  __syncthreads();
  for (int q = tid; q < 2 * B; q += 512) {
    int lr2 = q / B, b = q % B;
    int j2 = blockIdx.x * 2 + lr2;
    float z0 = zl[(lr2 * 4 + 0) * B + b], z1 = zl[(lr2 * 4 + 1) * B + b];
    float z2 = zl[(lr2 * 4 + 2) * B + b], z3 = zl[(lr2 * 4 + 3) * B + b];
    float c = sigf(z1) * cl[b * HSZ + j2] + sigf(z0) * tanhf(z2);
    cout[b * HSZ + j2] = c;
    hout[b * HSZ + j2] = sigf(z3) * tanhf(c);
  }
}

// layer-2 cell
template <int B>
__global__ void __launch_bounds__(512) k_dcell2(const float* __restrict__ Wih,
                                                const float* __restrict__ Whh,
                                                const float* __restrict__ bias,
                                                const float* __restrict__ x,
                                                const float* __restrict__ hin,
                                                const float* __restrict__ cin,
                                                float* __restrict__ hout, float* __restrict__ cout) {
  __shared__ float xl[B * HSZ], hl[B * HSZ], cl[B * HSZ], zl[8 * B];
  int tid = threadIdx.x;
  for (int i = tid; i < B * HSZ; i += 512) { xl[i] = x[i]; hl[i] = hin[i]; cl[i] = cin[i]; }
  __syncthreads();
  int wave = tid >> 6, lane = tid & 63;
  int lr = wave >> 2;
  int g  = wave & 3;
  int j  = blockIdx.x * 2 + lr;
  int row = j + (g << 9);
  const float4* wi = (const float4*)(Wih + (size_t)row * HSZ);
  const float4* wh = (const float4*)(Whh + (size_t)row * HSZ);
  float4 wi0 = wi[lane], wi1 = wi[lane + 64], wh0 = wh[lane], wh1 = wh[lane + 64];
  float bb = bias[row];
#pragma unroll
  for (int b = 0; b < B; ++b) {
    float4 xv0 = ((const float4*)(xl + b * HSZ))[lane];
    float4 xv1 = ((const float4*)(xl + b * HSZ))[lane + 64];
    float4 hv0 = ((const float4*)(hl + b * HSZ))[lane];
    float4 hv1 = ((const float4*)(hl + b * HSZ))[lane + 64];
    float acc = dot4(wi0, xv0) + dot4(wi1, xv1) + dot4(wh0, hv0) + dot4(wh1, hv1);
    float z = wsum(acc) + bb;
    if (lane == 0) zl[(lr * 4 + g) * B + b] = z;
  }
  __syncthreads();
  for (int q = tid; q < 2 * B; q += 512) {
    int lr2 = q / B, b = q % B;
    int j2 = blockIdx.x * 2 + lr2;
    float z0 = zl[(lr2 * 4 + 0) * B + b], z1 = zl[(lr2 * 4 + 1) * B + b];
    float z2 = zl[(lr2 * 4 + 2) * B + b], z3 = zl[(lr2 * 4 + 3) * B + b];
    float c = sigf(z1) * cl[b * HSZ + j2] + sigf(z0) * tanhf(z2);
    cout[b * HSZ + j2] = c;
    hout[b * HSZ + j2] = sigf(z3) * tanhf(c);
  }
}

// FUSED attention+feat (blocks 0..63 produce) -> flag sync -> logits (all 256 blocks).
// attfeat and logits math verbatim from round 10 (bit-exact twice).
template <int B>
__global__ void __launch_bounds__(512) k_atlg(const float* __restrict__ h2,
                                              const float* __restrict__ enc,
                                              const float* __restrict__ Wc,
                                              const float* __restrict__ Wout,
                                              const float* __restrict__ bout,
                                              float* __restrict__ feat,
                                              float* __restrict__ pm, float* __restrict__ ps,
                                              float* __restrict__ pv, int* __restrict__ pi,
                                              int* __restrict__ flags, int ep) {
  __shared__ float xs[BEAM * HSZ], at[BEAM * SEQ], xcs[BEAM * 1024];
  __shared__ float fst[BEAM * HSZ];
  int tid = threadIdx.x, wave = tid >> 6, lane = tid & 63;

  if (blockIdx.x < 64) {  // producer: attention + context + feat (verbatim)
    for (int i = tid; i < B * HSZ; i += 512) xs[i] = h2[i];
    __syncthreads();
    if (tid < B * SEQ) {
      int b = tid >> 6, s2 = tid & 63;
      const float* er = enc + (s2 + 1) * HSZ;
      const float* xb = xs + b * HSZ;
      float acc = 0.f;
      for (int e = 0; e < HSZ; e += 4) {
        float4 ev = *(const float4*)(er + e);
        acc += ev.x * xb[e] + ev.y * xb[e + 1] + ev.z * xb[e + 2] + ev.w * xb[e + 3];
      }
      at[tid] = acc;
    }
    __syncthreads();
    if (tid < B) {
      float m = -INFINITY;
      for (int s2 = 0; s2 < SEQ; ++s2) m = fmaxf(m, at[tid * SEQ + s2]);
      float s = 0.f;
      for (int s2 = 0; s2 < SEQ; ++s2) { float e = expf(at[tid * SEQ + s2] - m); at[tid * SEQ + s2] = e; s += e; }
      float inv = 1.f / s;
      for (int s2 = 0; s2 < SEQ; ++s2) at[tid * SEQ + s2] *= inv;
    }
    __syncthreads();
    if (tid < 128) {
      int h4 = tid * 4;
      float4 acc[B];
#pragma unroll
      for (int b = 0; b < B; ++b) acc[b] = make_float4(0.f, 0.f, 0.f, 0.f);
      for (int s2 = 0; s2 < SEQ; ++s2) {
        float4 ev = *(const float4*)(enc + (s2 + 1) * HSZ + h4);
#pragma unroll
        for (int b = 0; b < B; ++b) {
          float a = at[b * SEQ + s2];
          acc[b].x += a * ev.x; acc[b].y += a * ev.y; acc[b].z += a * ev.z; acc[b].w += a * ev.w;
        }
      }
#pragma unroll
      for (int b = 0; b < B; ++b) *(float4*)(xcs + b * 1024 + 512 + h4) = acc[b];
    }
    for (int i = tid; i < B * HSZ; i += 512) {
      int b = i >> 9, hcol = i & 511;
      xcs[b * 1024 + hcol] = xs[b * HSZ + hcol];
    }
    __syncthreads();
    int j = blockIdx.x * 8 + wave;  // 0..511
    const float4* w = (const float4*)(Wc + (size_t)j * 1024);
    float4 w0 = w[lane], w1 = w[lane + 64], w2 = w[lane + 128], w3 = w[lane + 192];
#pragma unroll
    for (int b = 0; b < B; ++b) {
      const float4* xb = (const float4*)(xcs + b * 1024);
      float acc = dot4(w0, xb[lane]) + dot4(w1, xb[lane + 64]) +
                  dot4(w2, xb[lane + 128]) + dot4(w3, xb[lane + 192]);
      acc = wsum(acc);
      if (lane == 0) agst(&feat[b * HSZ + j], tanhf(acc));
    }
    __syncthreads();  // drains vmcnt: feat stores at coherence point
    if (tid == 0) agsti(&flags[blockIdx.x * FLS], ep);
  }

  // all blocks: wait for the 64 producer flags (parallel poll, r8-validated pattern)
  if (tid < 64) {
    long it = 0;
    while (agldi(&flags[tid * FLS]) < ep && it < 200000000L) ++it;  // bailout beats a hang
  }
  asm volatile("" ::: "memory");
  __syncthreads();

  // logits (verbatim, feat via coherent loads)
  for (int i = tid; i < B * HSZ; i += 512) fst[i] = agld(&feat[i]);
  __syncthreads();
  int gid = blockIdx.x * 8 + wave;  // 0..2047
  float4 f0[B], f1[B];
#pragma unroll
  for (int b = 0; b < B; ++b) {
    f0[b] = ((const float4*)(fst + b * HSZ))[lane];
    f1[b] = ((const float4*)(fst + b * HSZ))[lane + 64];
  }
  float m[B], ss[B], tv[B][3];
  int tix[B][3];
#pragma unroll
  for (int b = 0; b < B; ++b) {
    m[b] = -INFINITY; ss[b] = 0.f;
#pragma unroll
    for (int k = 0; k < 3; ++k) { tv[b][k] = -INFINITY; tix[b][k] = 0x7fffffff; }
  }
  for (int k0 = 0; k0 < 16; k0 += 8) {
    float4 a0[8], a1[8]; float ab[8]; int vr[8];
#pragma unroll
    for (int u = 0; u < 8; ++u) {
      int v = gid + (k0 + u) * 2048;
      vr[u] = v;
      if (v < VOC) {
        const float4* wr = (const float4*)(Wout + (size_t)v * HSZ);
        a0[u] = wr[lane]; a1[u] = wr[lane + 64]; ab[u] = bout[v];
      } else {
        a0[u] = make_float4(0.f, 0.f, 0.f, 0.f); a1[u] = a0[u]; ab[u] = 0.f;
      }
    }
#pragma unroll
    for (int u = 0; u < 8; ++u) {
      if (vr[u] >= VOC) continue;  // wave-uniform
#pragma unroll
      for (int b = 0; b < B; ++b) {
        float acc = wsum(dot4(a0[u], f0[b]) + dot4(a1[u], f1[b])) + ab[u];
        float mo = m[b], mn = fmaxf(mo, acc);
        ss[b] = ss[b] * expf(mo - mn) + expf(acc - mn);
        m[b]  = mn;
        ins3(tv[b], tix[b], acc, vr[u]);
      }
    }
  }
  __shared__ float lm[8][3], lss[8][3], lv[8][3][3];
  __shared__ int li[8][3][3];
  if (lane == 0) {
#pragma unroll
    for (int b = 0; b < B; ++b) {
      lm[wave][b] = m[b]; lss[wave][b] = ss[b];
#pragma unroll
      for (int k = 0; k < 3; ++k) { lv[wave][b][k] = tv[b][k]; li[wave][b][k] = tix[b][k]; }
    }
  }
  __syncthreads();
  if (tid < B) {
    int b = tid;
    float M = -INFINITY;
#pragma unroll
    for (int w2 = 0; w2 < 8; ++w2) M = fmaxf(M, lm[w2][b]);
    float S = 0.f;
#pragma unroll
    for (int w2 = 0; w2 < 8; ++w2) S += lss[w2][b] * expf(lm[w2][b] - M);
    float bv[3] = {-INFINITY, -INFINITY, -INFINITY};
    int bi3[3]  = {0x7fffffff, 0x7fffffff, 0x7fffffff};
#pragma unroll
    for (int w2 = 0; w2 < 8; ++w2)
#pragma unroll
      for (int k = 0; k < 3; ++k) ins3(bv, bi3, lv[w2][b][k], li[w2][b][k]);
    int o = blockIdx.x * 3 + b;
    pm[o] = M; ps[o] = S;
#pragma unroll
    for (int k = 0; k < 3; ++k) { pv[o * 3 + k] = bv[k]; pi[o * 3 + k] = bi3[k]; }
  }
}

// tail: final merge + output write; 1 block x 256
__global__ void __launch_bounds__(256) k_tail(const float* __restrict__ pm,
                                              const float* __restrict__ ps,
                                              const float* __restrict__ pv,
                                              const int* __restrict__ pi,
                                              const float* __restrict__ scores_rd,
                                              const int* __restrict__ tokens_rd,
                                              int* __restrict__ bt, int* __restrict__ outp) {
  const int ti = TMAX - 2;
  __shared__ float sM[3], sS[3], sV[3][3], sScore[3];
  __shared__ int sI[3][3], sOrig[3], sTokOld[3], sKstar;
  int tid = threadIdx.x, wave = tid >> 6, lane = tid & 63;
  if (wave < 3) {
    int b = wave;
    float lm4[4], ls4[4];
    float M = -INFINITY;
#pragma unroll
    for (int q = 0; q < 4; ++q) {
      int blk2 = lane + q * 64;
      lm4[q] = pm[blk2 * 3 + b]; ls4[q] = ps[blk2 * 3 + b];
      M = fmaxf(M, lm4[q]);
    }
#pragma unroll
    for (int off = 32; off; off >>= 1) M = fmaxf(M, __shfl_xor(M, off, 64));
    float S = 0.f;
#pragma unroll
    for (int q = 0; q < 4; ++q) S += ls4[q] * expf(lm4[q] - M);
    S = wsum(S);
    float bv[3] = {-INFINITY, -INFINITY, -INFINITY};
    int bi3[3]  = {0x7fffffff, 0x7fffffff, 0x7fffffff};
#pragma unroll
    for (int q = 0; q < 4; ++q) {
      int blk2 = lane + q * 64;
#pragma unroll
      for (int k = 0; k < 3; ++k)
        ins3(bv, bi3, pv[(blk2 * 3 + b) * 3 + k], pi[(blk2 * 3 + b) * 3 + k]);
    }
#pragma unroll
    for (int off = 32; off; off >>= 1) {
      float ov[3]; int oi[3];
#pragma unroll
      for (int k = 0; k < 3; ++k) { ov[k] = __shfl_xor(bv[k], off, 64); oi[k] = __shfl_xor(bi3[k], off, 64); }
#pragma unroll
      for (int k = 0; k < 3; ++k) ins3(bv, bi3, ov[k], oi[k]);
    }
    if (lane == 0) {
      sM[b] = M; sS[b] = S;
#pragma unroll
      for (int k = 0; k < 3; ++k) { sV[b][k] = bv[k]; sI[b][k] = bi3[k]; }
    }
  }
  __syncthreads();
  if (tid == 0) {
    float osc[3];
    for (int b = 0; b < 3; ++b) { osc[b] = scores_rd[b]; sTokOld[b] = tokens_rd[b]; }
    float cum[9];
    for (int b = 0; b < 3; ++b) {
      float o = osc[b] - sM[b] - logf(sS[b]);
      for (int k = 0; k < 3; ++k) cum[b * 3 + k] = sV[b][k] + o;
    }
    bool used[9] = {false, false, false, false, false, false, false, false, false};
    for (int k = 0; k < 3; ++k) {
      int bf = 0; float bb = -INFINITY;
      for (int f = 0; f < 9; ++f)
        if (!used[f] && cum[f] > bb) { bb = cum[f]; bf = f; }
      used[bf] = true;
      sScore[k] = bb;
      sOrig[k] = bf / 3;
    }
    float bb = -INFINITY; int kk = 0;
    for (int k = 0; k < 3; ++k) if (sScore[k] > bb) { bb = sScore[k]; kk = k; }
    sKstar = kk;
  }
  __syncthreads();
  const int* src = bt + (ti & 1) * (BEAM * TMAX);
  int* dst = bt + ((ti + 1) & 1) * (BEAM * TMAX);
  for (int idx = tid; idx < BEAM * TMAX; idx += 256) {
    int k = idx / TMAX, jj = idx % TMAX, o = sOrig[k];
    dst[idx] = (jj == ti + 1) ? sTokOld[o] : src[o * TMAX + jj];
  }
  __syncthreads();
  for (int jj = tid; jj < TMAX; jj += 256) outp[jj] = dst[sKstar * TMAX + jj];
}

extern "C" void kernel_launch(void* const* d_in, const int* in_sizes, int n_in,
                              void* d_out, int out_size, void* d_ws, size_t ws_size,
                              hipStream_t stream) {
  const int*   seq     = (const int*)d_in[0];
  const float* emb_enc = (const float*)d_in[1];
  const float* Wih_enc = (const float*)d_in[2];
  const float* Whh_enc = (const float*)d_in[3];
  const float* b_enc   = (const float*)d_in[4];
  const float* emb_dec = (const float*)d_in[5];
  const float* Wih_dec = (const float*)d_in[6];
  const float* Whh_dec = (const float*)d_in[7];
  const float* b_dec   = (const float*)d_in[8];
  const float* W_c     = (const float*)d_in[9];
  const float* W_out   = (const float*)d_in[10];
  const float* b_out   = (const float*)d_in[11];
  const int*   bosp    = (const int*)d_in[14];

  int* flags = (int*)d_ws;                 // 64 lines x 64 B
  float* w = (float*)d_ws + 64 * FLS;
  float* xp1     = w; w += SEQ * H4;
  float* h1a     = w; w += (SEQ + 1) * HSZ;
  float* c1a     = w; w += (SEQ + 1) * HSZ;
  float* h2a     = w; w += (SEQ + 1) * HSZ;
  float* c2a     = w; w += (SEQ + 1) * HSZ;
  float* hdn1    = w; w += 2 * BEAM * HSZ;
  float* cdn1    = w; w += 2 * BEAM * HSZ;
  float* hdn2    = w; w += 2 * BEAM * HSZ;
  float* cdn2    = w; w += 2 * BEAM * HSZ;
  float* hd2p    = w; w += BEAM * HSZ;
  float* cd2p    = w; w += BEAM * HSZ;
  float* feat    = w; w += BEAM * HSZ;
  float* pm      = w; w += 256 * 3;
  float* ps      = w; w += 256 * 3;
  float* pv      = w; w += 256 * 3 * 3;
  float* sb      = w; w += 2 * 4;
  int* pi     = (int*)w; w += 256 * 3 * 3;
  int* tb     = (int*)w; w += 2 * 4;
  int* bt     = (int*)w; w += 2 * BEAM * TMAX + 4;
  int* outp   = (int*)d_out;

  hipMemsetAsync(flags, 0, 64 * FLS * sizeof(int), stream);

  k_xw1<<<256, 512, 0, stream>>>(Wih_enc, b_enc, emb_enc, seq, xp1);
  for (int s = 0; s <= SEQ; ++s)
    k_encslot<<<256, 512, 0, stream>>>(Whh_enc, Wih_enc + LOFF, Whh_enc + LOFF, b_enc + H4,
                                       xp1, h1a, c1a, h2a, c2a, s);

  for (int s = 0; s < TMAX; ++s) {
    int rp = (s - 1) & 1, wp = s & 1;
    if (s == 0) {
      k_dcell1<1, 1, 0><<<256, 512, 0, stream>>>(
          Wih_dec, Whh_dec, b_dec, emb_dec, bosp,
          h1a + SEQ * HSZ, c1a + SEQ * HSZ, h2a + SEQ * HSZ, c2a + SEQ * HSZ,
          pm, ps, pv, pi,
          hdn1 + 0, cdn1 + 0, hd2p, cd2p,
          sb, sb, tb, tb, bt, 0);
      k_dcell2<1><<<256, 512, 0, stream>>>(Wih_dec + LOFF, Whh_dec + LOFF, b_dec + H4,
                                           hdn1 + 0, hd2p, cd2p, hdn2 + 0, cdn2 + 0);
      k_atlg<1><<<256, 512, 0, stream>>>(hdn2 + 0, h2a, W_c, W_out, b_out, feat,
                                         pm, ps, pv, pi, flags, s + 1);
    } else {
      float* h1p = hdn1 + rp * BEAM * HSZ; float* c1p = cdn1 + rp * BEAM * HSZ;
      float* h2p = hdn2 + rp * BEAM * HSZ; float* c2p = cdn2 + rp * BEAM * HSZ;
      float* h1o = hdn1 + wp * BEAM * HSZ; float* c1o = cdn1 + wp * BEAM * HSZ;
      float* h2o = hdn2 + wp * BEAM * HSZ; float* c2o = cdn2 + wp * BEAM * HSZ;
      if (s == 1)
        k_dcell1<3, 1, 1><<<256, 512, 0, stream>>>(
            Wih_dec, Whh_dec, b_dec, emb_dec, bosp,
            h1p, c1p, h2p, c2p, pm, ps, pv, pi,
            h1o, c1o, hd2p, cd2p,
            sb + rp * 4, sb + wp * 4, tb + rp * 4, tb + wp * 4, bt, -1);
      else
        k_dcell1<3, 3, 2><<<256, 512, 0, stream>>>(
            Wih_dec, Whh_dec, b_dec, emb_dec, bosp,
            h1p, c1p, h2p, c2p, pm, ps, pv, pi,
            h1o, c1o, hd2p, cd2p,
            sb + rp * 4, sb + wp * 4, tb + rp * 4, tb + wp * 4, bt, s - 2);
      k_dcell2<3><<<256, 512, 0, stream>>>(Wih_dec + LOFF, Whh_dec + LOFF, b_dec + H4,
                                           h1o, hd2p, cd2p, h2o, c2o);
      k_atlg<3><<<256, 512, 0, stream>>>(h2o, h2a, W_c, W_out, b_out, feat,
                                         pm, ps, pv, pi, flags, s + 1);
    }
  }
  k_tail<<<1, 256, 0, stream>>>(pm, ps, pv, pi, sb + 4, tb + 4, bt, outp);
}